// Round 2
// baseline (607.722 us; speedup 1.0000x reference)
//
#include <hip/hip_runtime.h>
#include <hip/hip_bf16.h>
#include <math.h>

// ---------------------------------------------------------------------------
// Problem constants (from reference)
// ---------------------------------------------------------------------------
#define N_NODES 50000
#define N_EDGES 800000
#define NFEAT   512
#define NHID    256
#define NCLASS  128
#define N_UV    2048

// q24 fixed-point: scale 2^19, range +-16 (|S1|<~5 -> wide margin)
#define Q24_SCALE  524288.0f
#define Q24_INV    1.9073486328125e-6f

typedef __bf16    bf16x8 __attribute__((ext_vector_type(8)));
typedef short     s16x8  __attribute__((ext_vector_type(8)));
typedef float     f32x4  __attribute__((ext_vector_type(4)));

struct __attribute__((packed)) U3 { unsigned a, b, c; };  // 12B dwordx3 view

__device__ __forceinline__ unsigned short bf16_rn(float f) {
  unsigned u = __float_as_uint(f);
  u += 0x7fffu + ((u >> 16) & 1u);
  return (unsigned short)(u >> 16);
}
__device__ __forceinline__ float bf16_to_f(unsigned short h) {
  return __uint_as_float(((unsigned)h) << 16);
}
// 4 x 24-bit signed little-endian values from 3 dwords
__device__ __forceinline__ void unpack24(unsigned a, unsigned b, unsigned c,
                                         int& e0, int& e1, int& e2, int& e3) {
  e0 = ((int)(a << 8)) >> 8;
  e1 = ((int)((b << 16) | ((a >> 24) << 8))) >> 8;
  e2 = ((int)((c << 24) | ((b >> 16) << 8))) >> 8;
  e3 = ((int)c) >> 8;
}

// ---------------------------------------------------------------------------
// Split-bf16 MFMA GEMM: C[M,N] = A[M,K] @ BT[N,K]^T  (fp32-quality via
// Ahi*Bhi + Ahi*Blo + Alo*Bhi; 3-term REQUIRED — r6/r8 calibration: stage
// rms error amplifies ~280x into output absmax).
// 128x128 tile, BK=64, 256 thr, 4 waves 2x2, 4x4 mfma_f32_16x16x32_bf16
// x 2 K-substeps. 2-stage register pipeline for A.
//
// r12: BDIRECT — for the two big GEMMs the B operand is the pre-split
// weight matrix (W1 hi+lo = 512KB, W2 = 128KB): fully L2-resident, reused
// by all 391 M-blocks. Read B fragments straight from global (s16x8 at
// row*K+koff, L2-hit) and DELETE sBh/sBl: LDS 72->36KB -> 4 blocks/CU
// (was 2, OccupancyPercent 17%); ~64 VGPR of B staging freed ->
// launch_bounds(256,4) fits (round-4 spill was WITH B staging live).
// Counters r11 GEMM1: dur 105us, Occ 17%, Mfma 15%, VALU 20%, hbm 17% —
// nothing busy = latency-exposed barrier-synced loop at 2 waves/SIMD.
// OMODE: 0 = fp32 C, 1 = sigmoid fp32 C, 2 = interleaved q24 (3B/elem).
// ---------------------------------------------------------------------------
#define LDSPAD 72   // 64 + 8 shorts: keeps 16B alignment, breaks pow2 stride

template <bool ASPLIT, bool BSPLIT, bool BDIRECT, int OMODE>
__global__ __launch_bounds__(256, BDIRECT ? 4 : 2) void gemm_mfma_split(
    const float* __restrict__ Af,
    const unsigned short* __restrict__ Ahi, const unsigned short* __restrict__ Alo,
    const float* __restrict__ BTf,
    const unsigned short* __restrict__ BThi, const unsigned short* __restrict__ BTlo,
    float* __restrict__ C, unsigned char* __restrict__ Cq, int M, int N, int K) {
  __shared__ unsigned short sAh[128 * LDSPAD];
  __shared__ unsigned short sAl[128 * LDSPAD];
  __shared__ unsigned short sBh[BDIRECT ? 2 : 128 * LDSPAD];
  __shared__ unsigned short sBl[BDIRECT ? 2 : 128 * LDSPAD];

  const int tid  = threadIdx.x;
  const int lane = tid & 63;
  const int wave = tid >> 6;
  const int wm   = (wave >> 1) << 6;
  const int wn   = (wave & 1) << 6;
  const int lm   = lane & 15;
  const int quad = lane >> 4;
  const int m0   = blockIdx.y * 128;
  const int n0   = blockIdx.x * 128;

  // staging coordinates (BK=64)
  const int r32 = tid >> 4;            // 0..15 (fp32 path: 16 rows/pass, 8 passes)
  const int c32 = (tid & 15) * 4;      // float4 col 0..60
  const int r16 = tid >> 3;            // 0..31 (bf16 path: 32 rows/pass, 4 passes)
  const int c16 = (tid & 7) * 8;       // s16x8 col 0..56

  float4 pA[8]; s16x8 pAh[4], pAl[4];
  float4 pB[8]; s16x8 pBh[4], pBl[4];

  f32x4 acc[4][4];
#pragma unroll
  for (int i = 0; i < 4; ++i)
#pragma unroll
    for (int j = 0; j < 4; ++j)
#pragma unroll
      for (int r = 0; r < 4; ++r) acc[i][j][r] = 0.f;

#define LOAD_TILE(k0)                                                          \
  do {                                                                         \
    if (ASPLIT) {                                                              \
      _Pragma("unroll") for (int p = 0; p < 8; ++p) {                          \
        const int m = m0 + p * 16 + r32;                                       \
        pA[p] = make_float4(0.f, 0.f, 0.f, 0.f);                               \
        if (m < M) pA[p] = *(const float4*)&Af[(size_t)m * K + (k0) + c32];    \
      }                                                                        \
    } else {                                                                   \
      _Pragma("unroll") for (int p = 0; p < 4; ++p) {                          \
        const int m = m0 + p * 32 + r16;                                       \
        _Pragma("unroll") for (int e = 0; e < 8; ++e) { pAh[p][e] = 0; pAl[p][e] = 0; } \
        if (m < M) {                                                           \
          pAh[p] = *(const s16x8*)&Ahi[(size_t)m * K + (k0) + c16];            \
          pAl[p] = *(const s16x8*)&Alo[(size_t)m * K + (k0) + c16];            \
        }                                                                      \
      }                                                                        \
    }                                                                          \
    if (!BDIRECT) {                                                            \
      if (BSPLIT) {                                                            \
        _Pragma("unroll") for (int p = 0; p < 8; ++p) {                        \
          const int n = n0 + p * 16 + r32;                                     \
          pB[p] = *(const float4*)&BTf[(size_t)n * K + (k0) + c32];            \
        }                                                                      \
      } else {                                                                 \
        _Pragma("unroll") for (int p = 0; p < 4; ++p) {                        \
          pBh[p] = *(const s16x8*)&BThi[(size_t)(n0 + p * 32 + r16) * K + (k0) + c16]; \
          pBl[p] = *(const s16x8*)&BTlo[(size_t)(n0 + p * 32 + r16) * K + (k0) + c16]; \
        }                                                                      \
      }                                                                        \
    }                                                                          \
  } while (0)

#define SPLIT4(v, hv, lv)                                                      \
  hv.x = bf16_rn(v.x); lv.x = bf16_rn(v.x - bf16_to_f(hv.x));                  \
  hv.y = bf16_rn(v.y); lv.y = bf16_rn(v.y - bf16_to_f(hv.y));                  \
  hv.z = bf16_rn(v.z); lv.z = bf16_rn(v.z - bf16_to_f(hv.z));                  \
  hv.w = bf16_rn(v.w); lv.w = bf16_rn(v.w - bf16_to_f(hv.w));

#define STORE_TILE()                                                           \
  do {                                                                         \
    if (ASPLIT) {                                                              \
      _Pragma("unroll") for (int p = 0; p < 8; ++p) {                          \
        ushort4 hv, lv; SPLIT4(pA[p], hv, lv);                                 \
        const int row = p * 16 + r32;                                          \
        *(ushort4*)&sAh[row * LDSPAD + c32] = hv;                              \
        *(ushort4*)&sAl[row * LDSPAD + c32] = lv;                              \
      }                                                                        \
    } else {                                                                   \
      _Pragma("unroll") for (int p = 0; p < 4; ++p) {                          \
        const int row = p * 32 + r16;                                          \
        *(s16x8*)&sAh[row * LDSPAD + c16] = pAh[p];                            \
        *(s16x8*)&sAl[row * LDSPAD + c16] = pAl[p];                            \
      }                                                                        \
    }                                                                          \
    if (!BDIRECT) {                                                            \
      if (BSPLIT) {                                                            \
        _Pragma("unroll") for (int p = 0; p < 8; ++p) {                        \
          ushort4 hv, lv; SPLIT4(pB[p], hv, lv);                               \
          const int row = p * 16 + r32;                                        \
          *(ushort4*)&sBh[row * LDSPAD + c32] = hv;                            \
          *(ushort4*)&sBl[row * LDSPAD + c32] = lv;                            \
        }                                                                      \
      } else {                                                                 \
        _Pragma("unroll") for (int p = 0; p < 4; ++p) {                        \
          const int row = p * 32 + r16;                                        \
          *(s16x8*)&sBh[row * LDSPAD + c16] = pBh[p];                          \
          *(s16x8*)&sBl[row * LDSPAD + c16] = pBl[p];                          \
        }                                                                      \
      }                                                                        \
    }                                                                          \
  } while (0)

  LOAD_TILE(0);

  // B fragment row bases for the direct-from-global path (L2-resident)
  const unsigned short* Bhrow = BDIRECT ? BThi + (size_t)(n0 + wn + lm) * K : nullptr;
  const unsigned short* Blrow = BDIRECT ? BTlo + (size_t)(n0 + wn + lm) * K : nullptr;

  for (int k0 = 0; k0 < K; k0 += 64) {
    if (k0) __syncthreads();      // WAR: prior iter's frag reads complete
    STORE_TILE();
    __syncthreads();              // RAW: stores visible
    if (k0 + 64 < K) LOAD_TILE(k0 + 64);   // prefetch next tile

#pragma unroll
    for (int ks = 0; ks < 2; ++ks) {
      const int koff = ks * 32 + quad * 8;
      bf16x8 aH[4], aL[4], bH[4], bL[4];
#pragma unroll
      for (int i = 0; i < 4; ++i) {
        const int r = wm + i * 16 + lm;
        aH[i] = __builtin_bit_cast(bf16x8, *(const s16x8*)&sAh[r * LDSPAD + koff]);
        aL[i] = __builtin_bit_cast(bf16x8, *(const s16x8*)&sAl[r * LDSPAD + koff]);
      }
      if constexpr (BDIRECT) {
#pragma unroll
        for (int j = 0; j < 4; ++j) {
          const size_t off = (size_t)(j * 16) * K + k0 + koff;
          bH[j] = __builtin_bit_cast(bf16x8, *(const s16x8*)(Bhrow + off));
          bL[j] = __builtin_bit_cast(bf16x8, *(const s16x8*)(Blrow + off));
        }
      } else {
#pragma unroll
        for (int j = 0; j < 4; ++j) {
          const int r = wn + j * 16 + lm;
          bH[j] = __builtin_bit_cast(bf16x8, *(const s16x8*)&sBh[r * LDSPAD + koff]);
          bL[j] = __builtin_bit_cast(bf16x8, *(const s16x8*)&sBl[r * LDSPAD + koff]);
        }
      }
#pragma unroll
      for (int i = 0; i < 4; ++i)
#pragma unroll
        for (int j = 0; j < 4; ++j) {
          acc[i][j] = __builtin_amdgcn_mfma_f32_16x16x32_bf16(aH[i], bH[j], acc[i][j], 0, 0, 0);
          acc[i][j] = __builtin_amdgcn_mfma_f32_16x16x32_bf16(aH[i], bL[j], acc[i][j], 0, 0, 0);
          acc[i][j] = __builtin_amdgcn_mfma_f32_16x16x32_bf16(aL[i], bH[j], acc[i][j], 0, 0, 0);
        }
    }
  }

  // ---- epilogue: C/D layout col=lane&15, row=quad*4+reg ----
#pragma unroll
  for (int i = 0; i < 4; ++i)
#pragma unroll
    for (int j = 0; j < 4; ++j) {
      const int col = n0 + wn + j * 16 + lm;
#pragma unroll
      for (int r = 0; r < 4; ++r) {
        const int row = m0 + wm + i * 16 + quad * 4 + r;
        if (row < M) {
          float v = acc[i][j][r];
          if (OMODE == 1) {
            v = 1.f / (1.f + expf(-v));
            C[(size_t)row * N + col] = v;
          } else if (OMODE == 2) {
            int q = __float2int_rn(v * Q24_SCALE);
            q = q > 8388607 ? 8388607 : (q < -8388608 ? -8388608 : q);
            unsigned char* p = Cq + ((size_t)row * N + col) * 3;
            p[0] = (unsigned char)(q & 0xFF);
            p[1] = (unsigned char)((q >> 8) & 0xFF);
            p[2] = (unsigned char)((q >> 16) & 0xFF);
          } else {
            C[(size_t)row * N + col] = v;
          }
        }
      }
    }
#undef LOAD_TILE
#undef STORE_TILE
#undef SPLIT4
}

// ---------------------------------------------------------------------------
// Fused prep: row_ptr build (edge-parallel) + W1/W2 transpose+split.
// ---------------------------------------------------------------------------
__global__ __launch_bounds__(256) void prep_all(
    const int* __restrict__ rows, int* __restrict__ row_ptr,
    const float* __restrict__ W1, unsigned short* __restrict__ W1Thi,
    unsigned short* __restrict__ W1Tlo,
    const float* __restrict__ W2, unsigned short* __restrict__ W2Thi,
    unsigned short* __restrict__ W2Tlo) {
  const int idx = blockIdx.x * 256 + threadIdx.x;
  if (idx < N_EDGES) {
    const int r = rows[idx];
    const int rprev = (idx == 0) ? -1 : rows[idx - 1];
    for (int n = rprev + 1; n <= r; ++n) row_ptr[n] = idx;
    if (idx == N_EDGES - 1)
      for (int n = r + 1; n <= N_NODES; ++n) row_ptr[n] = N_EDGES;
  }
  if (idx < NFEAT * NHID) {   // W1T[n*K+k] = split(W1[k*N+n]), K=NFEAT N=NHID
    const int n = idx / NFEAT;
    const int k = idx - n * NFEAT;
    const float f = W1[(size_t)k * NHID + n];
    const unsigned short h = bf16_rn(f);
    W1Thi[idx] = h;
    W1Tlo[idx] = bf16_rn(f - bf16_to_f(h));
  }
  if (idx < NHID * NCLASS) {  // W2T, K=NHID N=NCLASS
    const int n = idx / NHID;
    const int k = idx - n * NHID;
    const float f = W2[(size_t)k * NCLASS + n];
    const unsigned short h = bf16_rn(f);
    W2Thi[idx] = h;
    W2Tlo[idx] = bf16_rn(f - bf16_to_f(h));
  }
}

// ---------------------------------------------------------------------------
// SpMM F=256, interleaved q24 source (768B rows): one wave per node, lane =
// 12B dwordx3 = 4 elems (full row per wave). fp32 accumulate.
// r11: 16-edge MASKED batches (was 8 + serial per-edge tail); moved spmm
// out of the top-5 dispatches. launch_bounds(256,4) caps VGPR at 128.
// Fused bias+relu+bf16 hi/lo split output.
// ---------------------------------------------------------------------------
__global__ __launch_bounds__(256, 4) void spmm256_q24_split(
    const unsigned char* __restrict__ Sq, const int* __restrict__ row_ptr,
    const int* __restrict__ cols, const float* __restrict__ vals,
    const float4* __restrict__ bias4,
    unsigned short* __restrict__ outHi, unsigned short* __restrict__ outLo) {
  const int wave = threadIdx.x >> 6;
  const int lane = threadIdx.x & 63;
  const int node = blockIdx.x * 4 + wave;

  // lo/hi are wave-uniform (node is): pin to SGPRs for scalar loop control
  const int lou = __builtin_amdgcn_readfirstlane(row_ptr[node]);
  const int hiu = __builtin_amdgcn_readfirstlane(row_ptr[node + 1]);

  float4 acc = make_float4(0.f, 0.f, 0.f, 0.f);
  const int lane12 = lane * 12;

  for (int base = lou; base < hiu; base += 16) {
    int   c[16];
    float w[16];   // pre-scaled by Q24_INV; 0 for masked slots
    if (base + 16 <= hiu) {           // full batch: unclamped contiguous loads
#pragma unroll
      for (int t = 0; t < 16; ++t) {
        c[t] = cols[base + t];
        w[t] = vals[base + t] * Q24_INV;
      }
    } else {                          // final partial batch: clamp+mask
#pragma unroll
      for (int t = 0; t < 16; ++t) {
        const int idx = base + t;
        const int ide = idx < hiu ? idx : hiu - 1;   // valid duplicate row
        c[t] = cols[ide];
        w[t] = idx < hiu ? vals[ide] * Q24_INV : 0.f;
      }
    }
    U3 d[16];
#pragma unroll
    for (int t = 0; t < 16; ++t)
      d[t] = *(const U3*)&Sq[(size_t)c[t] * (NHID * 3) + lane12];
#pragma unroll
    for (int t = 0; t < 16; ++t) {
      int e0, e1, e2, e3;
      unpack24(d[t].a, d[t].b, d[t].c, e0, e1, e2, e3);
      acc.x = fmaf(w[t], (float)e0, acc.x);
      acc.y = fmaf(w[t], (float)e1, acc.y);
      acc.z = fmaf(w[t], (float)e2, acc.z);
      acc.w = fmaf(w[t], (float)e3, acc.w);
    }
  }

  const float4 b = bias4[lane];
  acc.x = fmaxf(acc.x + b.x, 0.f);
  acc.y = fmaxf(acc.y + b.y, 0.f);
  acc.z = fmaxf(acc.z + b.z, 0.f);
  acc.w = fmaxf(acc.w + b.w, 0.f);

  ushort4 hv, lv;
  hv.x = bf16_rn(acc.x); lv.x = bf16_rn(acc.x - bf16_to_f(hv.x));
  hv.y = bf16_rn(acc.y); lv.y = bf16_rn(acc.y - bf16_to_f(hv.y));
  hv.z = bf16_rn(acc.z); lv.z = bf16_rn(acc.z - bf16_to_f(hv.z));
  hv.w = bf16_rn(acc.w); lv.w = bf16_rn(acc.w - bf16_to_f(hv.w));
  const size_t o = (size_t)node * NHID + lane * 4;
  *(ushort4*)&outHi[o] = hv;
  *(ushort4*)&outLo[o] = lv;
}

// ---------------------------------------------------------------------------
// SpMM F=128 over the 4096 LISTED nodes only (concat(u,v)) — Z is consumed
// only at rows u,v. One wave per list entry; half-waves alternate edges
// (32 lanes x float4 = full 512B row), 4-edge unroll per half. fp32 out ZUV.
// ---------------------------------------------------------------------------
__global__ __launch_bounds__(256) void spmm128_f32_list(
    const float4* __restrict__ S4, const int* __restrict__ row_ptr,
    const int* __restrict__ cols, const float* __restrict__ vals,
    const float4* __restrict__ bias4,
    const int* __restrict__ u, const int* __restrict__ v,
    float4* __restrict__ out4) {
  const int wave = threadIdx.x >> 6;
  const int lane = threadIdx.x & 63;
  const int half = lane >> 5;
  const int l32  = lane & 31;
  const int idx  = blockIdx.x * 4 + wave;          // 0..4095
  const int node = idx < N_UV ? u[idx] : v[idx - N_UV];

  const int lo = row_ptr[node];
  const int hi = row_ptr[node + 1];

  float4 acc = make_float4(0.f, 0.f, 0.f, 0.f);
  int e = lo + half;
  for (; e + 6 < hi; e += 8) {   // edges e, e+2, e+4, e+6 for this half
    int c[4]; float w[4];
#pragma unroll
    for (int t = 0; t < 4; ++t) { c[t] = cols[e + 2 * t]; w[t] = vals[e + 2 * t]; }
    float4 r[4];
#pragma unroll
    for (int t = 0; t < 4; ++t) r[t] = S4[(size_t)c[t] * 32 + l32];
#pragma unroll
    for (int t = 0; t < 4; ++t) {
      acc.x = fmaf(w[t], r[t].x, acc.x); acc.y = fmaf(w[t], r[t].y, acc.y);
      acc.z = fmaf(w[t], r[t].z, acc.z); acc.w = fmaf(w[t], r[t].w, acc.w);
    }
  }
  for (; e < hi; e += 2) {
    const int c = cols[e];
    const float w = vals[e];
    const float4 r = S4[(size_t)c * 32 + l32];
    acc.x = fmaf(w, r.x, acc.x); acc.y = fmaf(w, r.y, acc.y);
    acc.z = fmaf(w, r.z, acc.z); acc.w = fmaf(w, r.w, acc.w);
  }

  acc.x += __shfl_xor(acc.x, 32);
  acc.y += __shfl_xor(acc.y, 32);
  acc.z += __shfl_xor(acc.z, 32);
  acc.w += __shfl_xor(acc.w, 32);

  if (half == 0) {
    const float4 b = bias4[l32];
    acc.x += b.x; acc.y += b.y; acc.z += b.z; acc.w += b.w;
    out4[(size_t)idx * 32 + l32] = acc;
  }
}

// ---------------------------------------------------------------------------
// Launch
// ---------------------------------------------------------------------------
extern "C" void kernel_launch(void* const* d_in, const int* in_sizes, int n_in,
                              void* d_out, int out_size, void* d_ws, size_t ws_size,
                              hipStream_t stream) {
  const int*   u       = (const int*)  d_in[0];
  const int*   v       = (const int*)  d_in[1];
  const float* x       = (const float*)d_in[2];
  const int*   adj_row = (const int*)  d_in[3];
  const int*   adj_col = (const int*)  d_in[4];
  const float* adj_val = (const float*)d_in[5];
  const float* W1      = (const float*)d_in[6];
  const float* b1      = (const float*)d_in[7];
  const float* W2      = (const float*)d_in[8];
  const float* b2      = (const float*)d_in[9];
  const float* We      = (const float*)d_in[10];
  float* out = (float*)d_out;

  char* wsb = (char*)d_ws;
  // Region A [0, 51.2MB):
  //   S1q interleaved q24 38.4MB at [0, 38.4MB)
  //   after spmm1: S2 fp32 [0, 25.6MB), ZUV fp32 [25.6, 27.7MB)
  unsigned char* S1q = (unsigned char*)wsb;
  float* S2  = (float*)wsb;
  float* ZUV = (float*)(wsb + (size_t)N_NODES * NCLASS * sizeof(float));
  // Region B [51.2MB, 102.4MB): Hhi/Hlo; after GEMM2 dead -> ZU
  char* rB = wsb + (size_t)N_NODES * NHID * sizeof(float);
  unsigned short* Hhi = (unsigned short*)rB;
  unsigned short* Hlo = Hhi + (size_t)N_NODES * NHID;
  float* ZU = (float*)rB;                  // 2048*128
  // Split weights + row_ptr parked in d_out (dead until the final GEMM)
  unsigned short* W1Thi = (unsigned short*)out;
  unsigned short* W1Tlo = W1Thi + NHID * NFEAT;
  unsigned short* W2Thi = W1Tlo + NHID * NFEAT;
  unsigned short* W2Tlo = W2Thi + NCLASS * NHID;
  int* row_ptr = (int*)(W2Tlo + NCLASS * NHID);   // 50001 ints

  // 0) fused prep: row_ptr + weight transpose/split (one launch)
  prep_all<<<(N_EDGES + 255) / 256, 256, 0, stream>>>(
      adj_row, row_ptr, W1, W1Thi, W1Tlo, W2, W2Thi, W2Tlo);

  // 1) S1q = q24(x @ W1)  (MFMA split-bf16, A split on the fly, B direct)
  gemm_mfma_split<true, false, true, 2>
      <<<dim3(NHID / 128, (N_NODES + 127) / 128), 256, 0, stream>>>(
      x, nullptr, nullptr, nullptr, W1Thi, W1Tlo,
      nullptr, S1q, N_NODES, NHID, NFEAT);

  // 2) Hhi/Hlo = split(relu(A @ S1 + b1))   (interleaved q24 gather)
  spmm256_q24_split<<<N_NODES / 4, 256, 0, stream>>>(
      S1q, row_ptr, adj_col, adj_val, (const float4*)b1, Hhi, Hlo);

  // 3) S2 = H @ W2  (MFMA split-bf16, A pre-split, B direct, fp32 out)
  gemm_mfma_split<false, false, true, 0>
      <<<dim3(NCLASS / 128, (N_NODES + 127) / 128), 256, 0, stream>>>(
      nullptr, Hhi, Hlo, nullptr, W2Thi, W2Tlo,
      S2, nullptr, N_NODES, NCLASS, NHID);

  // 4) ZUV = (A @ S2 + b2)[concat(u,v)]  — only the 4096 rows the head uses
  spmm128_f32_list<<<(2 * N_UV) / 4, 256, 0, stream>>>(
      (const float4*)S2, row_ptr, adj_col, adj_val, (const float4*)b2,
      u, v, (float4*)ZUV);

  // 5) ZU = ZUV[0:2048] @ We^T  (BT = We as stored)
  gemm_mfma_split<true, true, false, 0>
      <<<dim3(NCLASS / 128, N_UV / 128), 256, 0, stream>>>(
      ZUV, nullptr, nullptr, We, nullptr, nullptr,
      ZU, nullptr, N_UV, NCLASS, NCLASS);

  // 6) out = sigmoid(ZU @ ZUV[2048:4096]^T)
  gemm_mfma_split<true, true, false, 1>
      <<<dim3(N_UV / 128, N_UV / 128), 256, 0, stream>>>(
      ZU, nullptr, nullptr, ZUV + (size_t)N_UV * NCLASS, nullptr, nullptr,
      out, nullptr, N_UV, N_UV, NCLASS);
}

// Round 3
// 395.338 us; speedup vs baseline: 1.5372x; 1.5372x over previous
//
#include <hip/hip_runtime.h>
#include <hip/hip_bf16.h>
#include <math.h>

// ---------------------------------------------------------------------------
// Problem constants (from reference)
// ---------------------------------------------------------------------------
#define N_NODES 50000
#define N_EDGES 800000
#define NFEAT   512
#define NHID    256
#define NCLASS  128
#define N_UV    2048

// q24 fixed-point: scale 2^19, range +-16 (|S1|<~5 -> wide margin)
#define Q24_SCALE  524288.0f
#define Q24_INV    1.9073486328125e-6f

typedef __bf16    bf16x8 __attribute__((ext_vector_type(8)));
typedef short     s16x8  __attribute__((ext_vector_type(8)));
typedef float     f32x4  __attribute__((ext_vector_type(4)));

struct __attribute__((packed)) U3 { unsigned a, b, c; };  // 12B dwordx3 view

__device__ __forceinline__ unsigned short bf16_rn(float f) {
  unsigned u = __float_as_uint(f);
  u += 0x7fffu + ((u >> 16) & 1u);
  return (unsigned short)(u >> 16);
}
__device__ __forceinline__ float bf16_to_f(unsigned short h) {
  return __uint_as_float(((unsigned)h) << 16);
}
// 4 x 24-bit signed little-endian values from 3 dwords
__device__ __forceinline__ void unpack24(unsigned a, unsigned b, unsigned c,
                                         int& e0, int& e1, int& e2, int& e3) {
  e0 = ((int)(a << 8)) >> 8;
  e1 = ((int)((b << 16) | ((a >> 24) << 8))) >> 8;
  e2 = ((int)((c << 24) | ((b >> 16) << 8))) >> 8;
  e3 = ((int)c) >> 8;
}

#define LDSPAD 72   // 64 + 8 shorts: keeps 16B alignment, breaks pow2 stride

// ---------------------------------------------------------------------------
// WIDE GEMM for the two big N_NODES-row GEMMs: C[M,N] = A[M,K] @ BT[N,K]^T
// split-bf16 3-term (Ahi*Bhi + Ahi*Blo + Alo*Bhi).
// r13: 512 threads, 8 waves 2Mx4N over a 128x128 tile -> per-wave 64x32:
//   acc 4x2 frags = 32 AGPR (r12's 4-wave layout needed 64 AGPR + 64 frag
//   VGPR and SPILLED under (256,4): WRITE 37.6->422MB, FETCH 102->327MB).
//   Budget now ~120 regs <= 128 cap of __launch_bounds__(512,4).
// B read DIRECT from global (BDIRECT): W1/W2 hi+lo are 512KB/128KB,
//   L2-resident, reused by all 391 M-blocks; no B LDS staging.
// LDS = sAh+sAl only = 36KB -> 2 blocks/CU = 16 waves/CU (2x r11's 8).
// ---------------------------------------------------------------------------
template <bool ASPLIT, int OMODE>
__global__ __launch_bounds__(512, 4) void gemm_mfma_wide(
    const float* __restrict__ Af,
    const unsigned short* __restrict__ Ahi, const unsigned short* __restrict__ Alo,
    const unsigned short* __restrict__ BThi, const unsigned short* __restrict__ BTlo,
    float* __restrict__ C, unsigned char* __restrict__ Cq, int M, int N, int K) {
  __shared__ unsigned short sAh[128 * LDSPAD];
  __shared__ unsigned short sAl[128 * LDSPAD];

  const int tid  = threadIdx.x;
  const int lane = tid & 63;
  const int wave = tid >> 6;           // 0..7
  const int wm   = (wave >> 2) << 6;   // 0 / 64
  const int wn   = (wave & 3) << 5;    // 0,32,64,96
  const int lm   = lane & 15;
  const int quad = lane >> 4;
  const int m0   = blockIdx.y * 128;
  const int n0   = blockIdx.x * 128;

  // staging coordinates (BK=64, 512 threads)
  const int r32 = tid >> 4;            // 0..31 (fp32: 32 rows/pass, 4 passes)
  const int c32 = (tid & 15) * 4;      // float4 col
  const int r16 = tid >> 3;            // 0..63 (bf16: 64 rows/pass, 2 passes)
  const int c16 = (tid & 7) * 8;       // s16x8 col

  float4 pA[4]; s16x8 pAh[2], pAl[2];

  f32x4 acc[4][2];
#pragma unroll
  for (int i = 0; i < 4; ++i)
#pragma unroll
    for (int j = 0; j < 2; ++j)
#pragma unroll
      for (int r = 0; r < 4; ++r) acc[i][j][r] = 0.f;

#define LOAD_TILE(k0)                                                          \
  do {                                                                         \
    if (ASPLIT) {                                                              \
      _Pragma("unroll") for (int p = 0; p < 4; ++p) {                          \
        const int m = m0 + p * 32 + r32;                                       \
        pA[p] = make_float4(0.f, 0.f, 0.f, 0.f);                               \
        if (m < M) pA[p] = *(const float4*)&Af[(size_t)m * K + (k0) + c32];    \
      }                                                                        \
    } else {                                                                   \
      _Pragma("unroll") for (int p = 0; p < 2; ++p) {                          \
        const int m = m0 + p * 64 + r16;                                       \
        _Pragma("unroll") for (int e = 0; e < 8; ++e) { pAh[p][e] = 0; pAl[p][e] = 0; } \
        if (m < M) {                                                           \
          pAh[p] = *(const s16x8*)&Ahi[(size_t)m * K + (k0) + c16];            \
          pAl[p] = *(const s16x8*)&Alo[(size_t)m * K + (k0) + c16];            \
        }                                                                      \
      }                                                                        \
    }                                                                          \
  } while (0)

#define SPLIT4W(v, hv, lv)                                                     \
  hv.x = bf16_rn(v.x); lv.x = bf16_rn(v.x - bf16_to_f(hv.x));                  \
  hv.y = bf16_rn(v.y); lv.y = bf16_rn(v.y - bf16_to_f(hv.y));                  \
  hv.z = bf16_rn(v.z); lv.z = bf16_rn(v.z - bf16_to_f(hv.z));                  \
  hv.w = bf16_rn(v.w); lv.w = bf16_rn(v.w - bf16_to_f(hv.w));

#define STORE_TILE()                                                           \
  do {                                                                         \
    if (ASPLIT) {                                                              \
      _Pragma("unroll") for (int p = 0; p < 4; ++p) {                          \
        ushort4 hv, lv; SPLIT4W(pA[p], hv, lv);                                \
        const int row = p * 32 + r32;                                          \
        *(ushort4*)&sAh[row * LDSPAD + c32] = hv;                              \
        *(ushort4*)&sAl[row * LDSPAD + c32] = lv;                              \
      }                                                                        \
    } else {                                                                   \
      _Pragma("unroll") for (int p = 0; p < 2; ++p) {                          \
        const int row = p * 64 + r16;                                          \
        *(s16x8*)&sAh[row * LDSPAD + c16] = pAh[p];                            \
        *(s16x8*)&sAl[row * LDSPAD + c16] = pAl[p];                            \
      }                                                                        \
    }                                                                          \
  } while (0)

  LOAD_TILE(0);

  // B fragment row bases (direct-from-global, L2-resident weights)
  const unsigned short* Bhrow = BThi + (size_t)(n0 + wn + lm) * K;
  const unsigned short* Blrow = BTlo + (size_t)(n0 + wn + lm) * K;

  for (int k0 = 0; k0 < K; k0 += 64) {
    if (k0) __syncthreads();      // WAR: prior iter's frag reads complete
    STORE_TILE();
    __syncthreads();              // RAW: stores visible
    if (k0 + 64 < K) LOAD_TILE(k0 + 64);   // prefetch next tile

#pragma unroll
    for (int ks = 0; ks < 2; ++ks) {
      const int koff = ks * 32 + quad * 8;
      bf16x8 aH[4], aL[4], bH[2], bL[2];
#pragma unroll
      for (int i = 0; i < 4; ++i) {
        const int r = wm + i * 16 + lm;
        aH[i] = __builtin_bit_cast(bf16x8, *(const s16x8*)&sAh[r * LDSPAD + koff]);
        aL[i] = __builtin_bit_cast(bf16x8, *(const s16x8*)&sAl[r * LDSPAD + koff]);
      }
#pragma unroll
      for (int j = 0; j < 2; ++j) {
        const size_t off = (size_t)(j * 16) * K + k0 + koff;
        bH[j] = __builtin_bit_cast(bf16x8, *(const s16x8*)(Bhrow + off));
        bL[j] = __builtin_bit_cast(bf16x8, *(const s16x8*)(Blrow + off));
      }
#pragma unroll
      for (int i = 0; i < 4; ++i)
#pragma unroll
        for (int j = 0; j < 2; ++j) {
          acc[i][j] = __builtin_amdgcn_mfma_f32_16x16x32_bf16(aH[i], bH[j], acc[i][j], 0, 0, 0);
          acc[i][j] = __builtin_amdgcn_mfma_f32_16x16x32_bf16(aH[i], bL[j], acc[i][j], 0, 0, 0);
          acc[i][j] = __builtin_amdgcn_mfma_f32_16x16x32_bf16(aL[i], bH[j], acc[i][j], 0, 0, 0);
        }
    }
  }

  // ---- epilogue: C/D layout col=lane&15, row=quad*4+reg ----
#pragma unroll
  for (int i = 0; i < 4; ++i)
#pragma unroll
    for (int j = 0; j < 2; ++j) {
      const int col = n0 + wn + j * 16 + lm;
#pragma unroll
      for (int r = 0; r < 4; ++r) {
        const int row = m0 + wm + i * 16 + quad * 4 + r;
        if (row < M) {
          float v = acc[i][j][r];
          if (OMODE == 2) {
            int q = __float2int_rn(v * Q24_SCALE);
            q = q > 8388607 ? 8388607 : (q < -8388608 ? -8388608 : q);
            unsigned char* p = Cq + ((size_t)row * N + col) * 3;
            p[0] = (unsigned char)(q & 0xFF);
            p[1] = (unsigned char)((q >> 8) & 0xFF);
            p[2] = (unsigned char)((q >> 16) & 0xFF);
          } else {
            C[(size_t)row * N + col] = v;
          }
        }
      }
    }
#undef LOAD_TILE
#undef STORE_TILE
#undef SPLIT4W
}

// ---------------------------------------------------------------------------
// Original 256-thread split-bf16 MFMA GEMM (r11, known-good) — used for the
// two small head GEMMs (5/6) where A and B both come from fp32 on the fly.
// 128x128 tile, BK=64, 4 waves 2x2, launch_bounds(256,2).
// OMODE: 0 = fp32 C, 1 = sigmoid fp32 C.
// ---------------------------------------------------------------------------
template <int OMODE>
__global__ __launch_bounds__(256, 2) void gemm_mfma_split(
    const float* __restrict__ Af, const float* __restrict__ BTf,
    float* __restrict__ C, int M, int N, int K) {
  __shared__ unsigned short sAh[128 * LDSPAD];
  __shared__ unsigned short sAl[128 * LDSPAD];
  __shared__ unsigned short sBh[128 * LDSPAD];
  __shared__ unsigned short sBl[128 * LDSPAD];

  const int tid  = threadIdx.x;
  const int lane = tid & 63;
  const int wave = tid >> 6;
  const int wm   = (wave >> 1) << 6;
  const int wn   = (wave & 1) << 6;
  const int lm   = lane & 15;
  const int quad = lane >> 4;
  const int m0   = blockIdx.y * 128;
  const int n0   = blockIdx.x * 128;

  const int r32 = tid >> 4;            // 0..15
  const int c32 = (tid & 15) * 4;      // float4 col

  float4 pA[8];
  float4 pB[8];

  f32x4 acc[4][4];
#pragma unroll
  for (int i = 0; i < 4; ++i)
#pragma unroll
    for (int j = 0; j < 4; ++j)
#pragma unroll
      for (int r = 0; r < 4; ++r) acc[i][j][r] = 0.f;

#define LOAD_TILE(k0)                                                          \
  do {                                                                         \
    _Pragma("unroll") for (int p = 0; p < 8; ++p) {                            \
      const int m = m0 + p * 16 + r32;                                         \
      pA[p] = make_float4(0.f, 0.f, 0.f, 0.f);                                 \
      if (m < M) pA[p] = *(const float4*)&Af[(size_t)m * K + (k0) + c32];      \
    }                                                                          \
    _Pragma("unroll") for (int p = 0; p < 8; ++p) {                            \
      const int n = n0 + p * 16 + r32;                                         \
      pB[p] = *(const float4*)&BTf[(size_t)n * K + (k0) + c32];                \
    }                                                                          \
  } while (0)

#define SPLIT4(v, hv, lv)                                                      \
  hv.x = bf16_rn(v.x); lv.x = bf16_rn(v.x - bf16_to_f(hv.x));                  \
  hv.y = bf16_rn(v.y); lv.y = bf16_rn(v.y - bf16_to_f(hv.y));                  \
  hv.z = bf16_rn(v.z); lv.z = bf16_rn(v.z - bf16_to_f(hv.z));                  \
  hv.w = bf16_rn(v.w); lv.w = bf16_rn(v.w - bf16_to_f(hv.w));

#define STORE_TILE()                                                           \
  do {                                                                         \
    _Pragma("unroll") for (int p = 0; p < 8; ++p) {                            \
      ushort4 hv, lv; SPLIT4(pA[p], hv, lv);                                   \
      const int row = p * 16 + r32;                                            \
      *(ushort4*)&sAh[row * LDSPAD + c32] = hv;                                \
      *(ushort4*)&sAl[row * LDSPAD + c32] = lv;                                \
    }                                                                          \
    _Pragma("unroll") for (int p = 0; p < 8; ++p) {                            \
      ushort4 hv, lv; SPLIT4(pB[p], hv, lv);                                   \
      const int row = p * 16 + r32;                                            \
      *(ushort4*)&sBh[row * LDSPAD + c32] = hv;                                \
      *(ushort4*)&sBl[row * LDSPAD + c32] = lv;                                \
    }                                                                          \
  } while (0)

  LOAD_TILE(0);

  for (int k0 = 0; k0 < K; k0 += 64) {
    if (k0) __syncthreads();
    STORE_TILE();
    __syncthreads();
    if (k0 + 64 < K) LOAD_TILE(k0 + 64);

#pragma unroll
    for (int ks = 0; ks < 2; ++ks) {
      const int koff = ks * 32 + quad * 8;
      bf16x8 aH[4], aL[4], bH[4], bL[4];
#pragma unroll
      for (int i = 0; i < 4; ++i) {
        const int r = wm + i * 16 + lm;
        aH[i] = __builtin_bit_cast(bf16x8, *(const s16x8*)&sAh[r * LDSPAD + koff]);
        aL[i] = __builtin_bit_cast(bf16x8, *(const s16x8*)&sAl[r * LDSPAD + koff]);
      }
#pragma unroll
      for (int j = 0; j < 4; ++j) {
        const int r = wn + j * 16 + lm;
        bH[j] = __builtin_bit_cast(bf16x8, *(const s16x8*)&sBh[r * LDSPAD + koff]);
        bL[j] = __builtin_bit_cast(bf16x8, *(const s16x8*)&sBl[r * LDSPAD + koff]);
      }
#pragma unroll
      for (int i = 0; i < 4; ++i)
#pragma unroll
        for (int j = 0; j < 4; ++j) {
          acc[i][j] = __builtin_amdgcn_mfma_f32_16x16x32_bf16(aH[i], bH[j], acc[i][j], 0, 0, 0);
          acc[i][j] = __builtin_amdgcn_mfma_f32_16x16x32_bf16(aH[i], bL[j], acc[i][j], 0, 0, 0);
          acc[i][j] = __builtin_amdgcn_mfma_f32_16x16x32_bf16(aL[i], bH[j], acc[i][j], 0, 0, 0);
        }
    }
  }

#pragma unroll
  for (int i = 0; i < 4; ++i)
#pragma unroll
    for (int j = 0; j < 4; ++j) {
      const int col = n0 + wn + j * 16 + lm;
#pragma unroll
      for (int r = 0; r < 4; ++r) {
        const int row = m0 + wm + i * 16 + quad * 4 + r;
        if (row < M) {
          float v = acc[i][j][r];
          if (OMODE == 1) v = 1.f / (1.f + expf(-v));
          C[(size_t)row * N + col] = v;
        }
      }
    }
#undef LOAD_TILE
#undef STORE_TILE
#undef SPLIT4
}

// ---------------------------------------------------------------------------
// Fused prep: row_ptr build (edge-parallel) + W1/W2 transpose+split.
// ---------------------------------------------------------------------------
__global__ __launch_bounds__(256) void prep_all(
    const int* __restrict__ rows, int* __restrict__ row_ptr,
    const float* __restrict__ W1, unsigned short* __restrict__ W1Thi,
    unsigned short* __restrict__ W1Tlo,
    const float* __restrict__ W2, unsigned short* __restrict__ W2Thi,
    unsigned short* __restrict__ W2Tlo) {
  const int idx = blockIdx.x * 256 + threadIdx.x;
  if (idx < N_EDGES) {
    const int r = rows[idx];
    const int rprev = (idx == 0) ? -1 : rows[idx - 1];
    for (int n = rprev + 1; n <= r; ++n) row_ptr[n] = idx;
    if (idx == N_EDGES - 1)
      for (int n = r + 1; n <= N_NODES; ++n) row_ptr[n] = N_EDGES;
  }
  if (idx < NFEAT * NHID) {   // W1T[n*K+k] = split(W1[k*N+n]), K=NFEAT N=NHID
    const int n = idx / NFEAT;
    const int k = idx - n * NFEAT;
    const float f = W1[(size_t)k * NHID + n];
    const unsigned short h = bf16_rn(f);
    W1Thi[idx] = h;
    W1Tlo[idx] = bf16_rn(f - bf16_to_f(h));
  }
  if (idx < NHID * NCLASS) {  // W2T, K=NHID N=NCLASS
    const int n = idx / NHID;
    const int k = idx - n * NHID;
    const float f = W2[(size_t)k * NCLASS + n];
    const unsigned short h = bf16_rn(f);
    W2Thi[idx] = h;
    W2Tlo[idx] = bf16_rn(f - bf16_to_f(h));
  }
}

// ---------------------------------------------------------------------------
// SpMM F=256, interleaved q24 source (768B rows): one wave per node, lane =
// 12B dwordx3 = 4 elems (full row per wave). fp32 accumulate.
// 16-edge MASKED batches (r11). Fused bias+relu+bf16 hi/lo split output.
// ---------------------------------------------------------------------------
__global__ __launch_bounds__(256, 4) void spmm256_q24_split(
    const unsigned char* __restrict__ Sq, const int* __restrict__ row_ptr,
    const int* __restrict__ cols, const float* __restrict__ vals,
    const float4* __restrict__ bias4,
    unsigned short* __restrict__ outHi, unsigned short* __restrict__ outLo) {
  const int wave = threadIdx.x >> 6;
  const int lane = threadIdx.x & 63;
  const int node = blockIdx.x * 4 + wave;

  // lo/hi are wave-uniform (node is): pin to SGPRs for scalar loop control
  const int lou = __builtin_amdgcn_readfirstlane(row_ptr[node]);
  const int hiu = __builtin_amdgcn_readfirstlane(row_ptr[node + 1]);

  float4 acc = make_float4(0.f, 0.f, 0.f, 0.f);
  const int lane12 = lane * 12;

  for (int base = lou; base < hiu; base += 16) {
    int   c[16];
    float w[16];   // pre-scaled by Q24_INV; 0 for masked slots
    if (base + 16 <= hiu) {           // full batch: unclamped contiguous loads
#pragma unroll
      for (int t = 0; t < 16; ++t) {
        c[t] = cols[base + t];
        w[t] = vals[base + t] * Q24_INV;
      }
    } else {                          // final partial batch: clamp+mask
#pragma unroll
      for (int t = 0; t < 16; ++t) {
        const int idx = base + t;
        const int ide = idx < hiu ? idx : hiu - 1;   // valid duplicate row
        c[t] = cols[ide];
        w[t] = idx < hiu ? vals[ide] * Q24_INV : 0.f;
      }
    }
    U3 d[16];
#pragma unroll
    for (int t = 0; t < 16; ++t)
      d[t] = *(const U3*)&Sq[(size_t)c[t] * (NHID * 3) + lane12];
#pragma unroll
    for (int t = 0; t < 16; ++t) {
      int e0, e1, e2, e3;
      unpack24(d[t].a, d[t].b, d[t].c, e0, e1, e2, e3);
      acc.x = fmaf(w[t], (float)e0, acc.x);
      acc.y = fmaf(w[t], (float)e1, acc.y);
      acc.z = fmaf(w[t], (float)e2, acc.z);
      acc.w = fmaf(w[t], (float)e3, acc.w);
    }
  }

  const float4 b = bias4[lane];
  acc.x = fmaxf(acc.x + b.x, 0.f);
  acc.y = fmaxf(acc.y + b.y, 0.f);
  acc.z = fmaxf(acc.z + b.z, 0.f);
  acc.w = fmaxf(acc.w + b.w, 0.f);

  ushort4 hv, lv;
  hv.x = bf16_rn(acc.x); lv.x = bf16_rn(acc.x - bf16_to_f(hv.x));
  hv.y = bf16_rn(acc.y); lv.y = bf16_rn(acc.y - bf16_to_f(hv.y));
  hv.z = bf16_rn(acc.z); lv.z = bf16_rn(acc.z - bf16_to_f(hv.z));
  hv.w = bf16_rn(acc.w); lv.w = bf16_rn(acc.w - bf16_to_f(hv.w));
  const size_t o = (size_t)node * NHID + lane * 4;
  *(ushort4*)&outHi[o] = hv;
  *(ushort4*)&outLo[o] = lv;
}

// ---------------------------------------------------------------------------
// SpMM F=128 over the 4096 LISTED nodes only (concat(u,v)) — Z is consumed
// only at rows u,v. One wave per list entry; half-waves alternate edges
// (32 lanes x float4 = full 512B row), 4-edge unroll per half. fp32 out ZUV.
// ---------------------------------------------------------------------------
__global__ __launch_bounds__(256) void spmm128_f32_list(
    const float4* __restrict__ S4, const int* __restrict__ row_ptr,
    const int* __restrict__ cols, const float* __restrict__ vals,
    const float4* __restrict__ bias4,
    const int* __restrict__ u, const int* __restrict__ v,
    float4* __restrict__ out4) {
  const int wave = threadIdx.x >> 6;
  const int lane = threadIdx.x & 63;
  const int half = lane >> 5;
  const int l32  = lane & 31;
  const int idx  = blockIdx.x * 4 + wave;          // 0..4095
  const int node = idx < N_UV ? u[idx] : v[idx - N_UV];

  const int lo = row_ptr[node];
  const int hi = row_ptr[node + 1];

  float4 acc = make_float4(0.f, 0.f, 0.f, 0.f);
  int e = lo + half;
  for (; e + 6 < hi; e += 8) {   // edges e, e+2, e+4, e+6 for this half
    int c[4]; float w[4];
#pragma unroll
    for (int t = 0; t < 4; ++t) { c[t] = cols[e + 2 * t]; w[t] = vals[e + 2 * t]; }
    float4 r[4];
#pragma unroll
    for (int t = 0; t < 4; ++t) r[t] = S4[(size_t)c[t] * 32 + l32];
#pragma unroll
    for (int t = 0; t < 4; ++t) {
      acc.x = fmaf(w[t], r[t].x, acc.x); acc.y = fmaf(w[t], r[t].y, acc.y);
      acc.z = fmaf(w[t], r[t].z, acc.z); acc.w = fmaf(w[t], r[t].w, acc.w);
    }
  }
  for (; e < hi; e += 2) {
    const int c = cols[e];
    const float w = vals[e];
    const float4 r = S4[(size_t)c * 32 + l32];
    acc.x = fmaf(w, r.x, acc.x); acc.y = fmaf(w, r.y, acc.y);
    acc.z = fmaf(w, r.z, acc.z); acc.w = fmaf(w, r.w, acc.w);
  }

  acc.x += __shfl_xor(acc.x, 32);
  acc.y += __shfl_xor(acc.y, 32);
  acc.z += __shfl_xor(acc.z, 32);
  acc.w += __shfl_xor(acc.w, 32);

  if (half == 0) {
    const float4 b = bias4[l32];
    acc.x += b.x; acc.y += b.y; acc.z += b.z; acc.w += b.w;
    out4[(size_t)idx * 32 + l32] = acc;
  }
}

// ---------------------------------------------------------------------------
// Launch
// ---------------------------------------------------------------------------
extern "C" void kernel_launch(void* const* d_in, const int* in_sizes, int n_in,
                              void* d_out, int out_size, void* d_ws, size_t ws_size,
                              hipStream_t stream) {
  const int*   u       = (const int*)  d_in[0];
  const int*   v       = (const int*)  d_in[1];
  const float* x       = (const float*)d_in[2];
  const int*   adj_row = (const int*)  d_in[3];
  const int*   adj_col = (const int*)  d_in[4];
  const float* adj_val = (const float*)d_in[5];
  const float* W1      = (const float*)d_in[6];
  const float* b1      = (const float*)d_in[7];
  const float* W2      = (const float*)d_in[8];
  const float* b2      = (const float*)d_in[9];
  const float* We      = (const float*)d_in[10];
  float* out = (float*)d_out;

  char* wsb = (char*)d_ws;
  // Region A [0, 51.2MB):
  //   S1q interleaved q24 38.4MB at [0, 38.4MB)
  //   after spmm1: S2 fp32 [0, 25.6MB), ZUV fp32 [25.6, 27.7MB)
  unsigned char* S1q = (unsigned char*)wsb;
  float* S2  = (float*)wsb;
  float* ZUV = (float*)(wsb + (size_t)N_NODES * NCLASS * sizeof(float));
  // Region B [51.2MB, 102.4MB): Hhi/Hlo; after GEMM2 dead -> ZU
  char* rB = wsb + (size_t)N_NODES * NHID * sizeof(float);
  unsigned short* Hhi = (unsigned short*)rB;
  unsigned short* Hlo = Hhi + (size_t)N_NODES * NHID;
  float* ZU = (float*)rB;                  // 2048*128
  // Split weights + row_ptr parked in d_out (dead until the final GEMM)
  unsigned short* W1Thi = (unsigned short*)out;
  unsigned short* W1Tlo = W1Thi + NHID * NFEAT;
  unsigned short* W2Thi = W1Tlo + NHID * NFEAT;
  unsigned short* W2Tlo = W2Thi + NCLASS * NHID;
  int* row_ptr = (int*)(W2Tlo + NCLASS * NHID);   // 50001 ints

  // 0) fused prep: row_ptr + weight transpose/split (one launch)
  prep_all<<<(N_EDGES + 255) / 256, 256, 0, stream>>>(
      adj_row, row_ptr, W1, W1Thi, W1Tlo, W2, W2Thi, W2Tlo);

  // 1) S1q = q24(x @ W1)  (wide MFMA, A split on the fly, B direct)
  gemm_mfma_wide<true, 2>
      <<<dim3(NHID / 128, (N_NODES + 127) / 128), 512, 0, stream>>>(
      x, nullptr, nullptr, W1Thi, W1Tlo,
      nullptr, S1q, N_NODES, NHID, NFEAT);

  // 2) Hhi/Hlo = split(relu(A @ S1 + b1))   (interleaved q24 gather)
  spmm256_q24_split<<<N_NODES / 4, 256, 0, stream>>>(
      S1q, row_ptr, adj_col, adj_val, (const float4*)b1, Hhi, Hlo);

  // 3) S2 = H @ W2  (wide MFMA, A pre-split, B direct, fp32 out)
  gemm_mfma_wide<false, 0>
      <<<dim3(NCLASS / 128, (N_NODES + 127) / 128), 512, 0, stream>>>(
      nullptr, Hhi, Hlo, W2Thi, W2Tlo,
      S2, nullptr, N_NODES, NCLASS, NHID);

  // 4) ZUV = (A @ S2 + b2)[concat(u,v)]  — only the 4096 rows the head uses
  spmm128_f32_list<<<(2 * N_UV) / 4, 256, 0, stream>>>(
      (const float4*)S2, row_ptr, adj_col, adj_val, (const float4*)b2,
      u, v, (float4*)ZUV);

  // 5) ZU = ZUV[0:2048] @ We^T  (BT = We as stored)
  gemm_mfma_split<0>
      <<<dim3(NCLASS / 128, N_UV / 128), 256, 0, stream>>>(
      ZUV, We, ZU, N_UV, NCLASS, NCLASS);

  // 6) out = sigmoid(ZU @ ZUV[2048:4096]^T)
  gemm_mfma_split<1>
      <<<dim3(N_UV / 128, N_UV / 128), 256, 0, stream>>>(
      ZU, ZUV + (size_t)N_UV * NCLASS, out, N_UV, N_UV, NCLASS);
}

// Round 5
// 385.339 us; speedup vs baseline: 1.5771x; 1.0259x over previous
//
#include <hip/hip_runtime.h>
#include <hip/hip_bf16.h>
#include <math.h>

// ---------------------------------------------------------------------------
// Problem constants (from reference)
// ---------------------------------------------------------------------------
#define N_NODES 50000
#define N_EDGES 800000
#define NFEAT   512
#define NHID    256
#define NCLASS  128
#define N_UV    2048

// q24 fixed-point: scale 2^19, range +-16 (|S1|<~5 -> wide margin)
#define Q24_SCALE  524288.0f
#define Q24_INV    1.9073486328125e-6f

typedef __bf16    bf16x8 __attribute__((ext_vector_type(8)));
typedef short     s16x8  __attribute__((ext_vector_type(8)));
typedef float     f32x4  __attribute__((ext_vector_type(4)));

struct __attribute__((packed)) U3 { unsigned a, b, c; };  // 12B dwordx3 view

__device__ __forceinline__ unsigned short bf16_rn(float f) {
  unsigned u = __float_as_uint(f);
  u += 0x7fffu + ((u >> 16) & 1u);
  return (unsigned short)(u >> 16);
}
__device__ __forceinline__ float bf16_to_f(unsigned short h) {
  return __uint_as_float(((unsigned)h) << 16);
}
// 4 x 24-bit signed little-endian values from 3 dwords
__device__ __forceinline__ void unpack24(unsigned a, unsigned b, unsigned c,
                                         int& e0, int& e1, int& e2, int& e3) {
  e0 = ((int)(a << 8)) >> 8;
  e1 = ((int)((b << 16) | ((a >> 24) << 8))) >> 8;
  e2 = ((int)((c << 24) | ((b >> 16) << 8))) >> 8;
  e3 = ((int)c) >> 8;
}

#define LDSPAD 72   // 64 + 8 shorts: keeps 16B alignment, breaks pow2 stride

// ---------------------------------------------------------------------------
// WIDE GEMM for the two big N_NODES-row GEMMs: C[M,N] = A[M,K] @ BT[N,K]^T
// split-bf16 3-term (Ahi*Bhi + Ahi*Blo + Alo*Bhi).
// 512 threads, 8 waves 2Mx4N over a 128x128 tile -> per-wave 64x32:
//   acc 4x2 frags = 32 AGPR; fits (512,4)'s 128-reg cap (r13: VGPR=60,
//   no spill, Occ 30%).
// B read DIRECT from global (W1/W2 hi+lo are 512KB/128KB, L2-resident).
// LDS = sAh+sAl only = 36KB -> 2 blocks/CU = 16 waves/CU.
//
// r14 (resubmitted r15 — infra failure, no counters): B-FRAGMENT LOADS
// HOISTED BEFORE THE A PREFETCH. vmcnt is FIFO: r13 issued B loads AFTER
// LOAD_TILE(k0+64), so the s_waitcnt for B before the first MFMA drained
// the whole next-tile A prefetch -> serialized pipeline (MfmaUtil 13%,
// dur 117us despite 2x occupancy). Loading all 8 B frags (32 VGPR) before
// the prefetch makes the B-wait vmcnt(#A-loads): B completes while A
// stays in flight — restores the overlap that B-in-LDS gave via lgkmcnt.
// ---------------------------------------------------------------------------
template <bool ASPLIT, int OMODE>
__global__ __launch_bounds__(512, 4) void gemm_mfma_wide(
    const float* __restrict__ Af,
    const unsigned short* __restrict__ Ahi, const unsigned short* __restrict__ Alo,
    const unsigned short* __restrict__ BThi, const unsigned short* __restrict__ BTlo,
    float* __restrict__ C, unsigned char* __restrict__ Cq, int M, int N, int K) {
  __shared__ unsigned short sAh[128 * LDSPAD];
  __shared__ unsigned short sAl[128 * LDSPAD];

  const int tid  = threadIdx.x;
  const int lane = tid & 63;
  const int wave = tid >> 6;           // 0..7
  const int wm   = (wave >> 2) << 6;   // 0 / 64
  const int wn   = (wave & 3) << 5;    // 0,32,64,96
  const int lm   = lane & 15;
  const int quad = lane >> 4;
  const int m0   = blockIdx.y * 128;
  const int n0   = blockIdx.x * 128;

  // staging coordinates (BK=64, 512 threads)
  const int r32 = tid >> 4;            // 0..31 (fp32: 32 rows/pass, 4 passes)
  const int c32 = (tid & 15) * 4;      // float4 col
  const int r16 = tid >> 3;            // 0..63 (bf16: 64 rows/pass, 2 passes)
  const int c16 = (tid & 7) * 8;       // s16x8 col

  float4 pA[4]; s16x8 pAh[2], pAl[2];

  f32x4 acc[4][2];
#pragma unroll
  for (int i = 0; i < 4; ++i)
#pragma unroll
    for (int j = 0; j < 2; ++j)
#pragma unroll
      for (int r = 0; r < 4; ++r) acc[i][j][r] = 0.f;

#define LOAD_TILE(k0)                                                          \
  do {                                                                         \
    if (ASPLIT) {                                                              \
      _Pragma("unroll") for (int p = 0; p < 4; ++p) {                          \
        const int m = m0 + p * 32 + r32;                                       \
        pA[p] = make_float4(0.f, 0.f, 0.f, 0.f);                               \
        if (m < M) pA[p] = *(const float4*)&Af[(size_t)m * K + (k0) + c32];    \
      }                                                                        \
    } else {                                                                   \
      _Pragma("unroll") for (int p = 0; p < 2; ++p) {                          \
        const int m = m0 + p * 64 + r16;                                       \
        _Pragma("unroll") for (int e = 0; e < 8; ++e) { pAh[p][e] = 0; pAl[p][e] = 0; } \
        if (m < M) {                                                           \
          pAh[p] = *(const s16x8*)&Ahi[(size_t)m * K + (k0) + c16];            \
          pAl[p] = *(const s16x8*)&Alo[(size_t)m * K + (k0) + c16];            \
        }                                                                      \
      }                                                                        \
    }                                                                          \
  } while (0)

#define SPLIT4W(v, hv, lv)                                                     \
  hv.x = bf16_rn(v.x); lv.x = bf16_rn(v.x - bf16_to_f(hv.x));                  \
  hv.y = bf16_rn(v.y); lv.y = bf16_rn(v.y - bf16_to_f(hv.y));                  \
  hv.z = bf16_rn(v.z); lv.z = bf16_rn(v.z - bf16_to_f(hv.z));                  \
  hv.w = bf16_rn(v.w); lv.w = bf16_rn(v.w - bf16_to_f(hv.w));

#define STORE_TILE()                                                           \
  do {                                                                         \
    if (ASPLIT) {                                                              \
      _Pragma("unroll") for (int p = 0; p < 4; ++p) {                          \
        ushort4 hv, lv; SPLIT4W(pA[p], hv, lv);                                \
        const int row = p * 32 + r32;                                          \
        *(ushort4*)&sAh[row * LDSPAD + c32] = hv;                              \
        *(ushort4*)&sAl[row * LDSPAD + c32] = lv;                              \
      }                                                                        \
    } else {                                                                   \
      _Pragma("unroll") for (int p = 0; p < 2; ++p) {                          \
        const int row = p * 64 + r16;                                          \
        *(s16x8*)&sAh[row * LDSPAD + c16] = pAh[p];                            \
        *(s16x8*)&sAl[row * LDSPAD + c16] = pAl[p];                            \
      }                                                                        \
    }                                                                          \
  } while (0)

  LOAD_TILE(0);

  // B fragment row bases (direct-from-global, L2-resident weights)
  const unsigned short* Bhrow = BThi + (size_t)(n0 + wn + lm) * K;
  const unsigned short* Blrow = BTlo + (size_t)(n0 + wn + lm) * K;

  for (int k0 = 0; k0 < K; k0 += 64) {
    if (k0) __syncthreads();      // WAR: prior iter's frag reads complete
    STORE_TILE();
    __syncthreads();              // RAW: stores visible

    // B fragments for THIS K-tile, issued BEFORE the A prefetch: vmcnt is
    // FIFO, so the MFMA's wait for B becomes vmcnt(#A-loads) and the
    // A prefetch stays in flight across the whole compute phase.
    bf16x8 bH[2][2], bL[2][2];
#pragma unroll
    for (int ks = 0; ks < 2; ++ks)
#pragma unroll
      for (int j = 0; j < 2; ++j) {
        const size_t off = (size_t)(j * 16) * K + k0 + ks * 32 + quad * 8;
        bH[ks][j] = __builtin_bit_cast(bf16x8, *(const s16x8*)(Bhrow + off));
        bL[ks][j] = __builtin_bit_cast(bf16x8, *(const s16x8*)(Blrow + off));
      }

    if (k0 + 64 < K) LOAD_TILE(k0 + 64);   // prefetch next tile (newest vmem)

#pragma unroll
    for (int ks = 0; ks < 2; ++ks) {
      const int koff = ks * 32 + quad * 8;
#pragma unroll
      for (int i = 0; i < 4; ++i) {
        const int r = wm + i * 16 + lm;
        const bf16x8 aH = __builtin_bit_cast(bf16x8, *(const s16x8*)&sAh[r * LDSPAD + koff]);
        const bf16x8 aL = __builtin_bit_cast(bf16x8, *(const s16x8*)&sAl[r * LDSPAD + koff]);
#pragma unroll
        for (int j = 0; j < 2; ++j) {
          acc[i][j] = __builtin_amdgcn_mfma_f32_16x16x32_bf16(aH, bH[ks][j], acc[i][j], 0, 0, 0);
          acc[i][j] = __builtin_amdgcn_mfma_f32_16x16x32_bf16(aH, bL[ks][j], acc[i][j], 0, 0, 0);
          acc[i][j] = __builtin_amdgcn_mfma_f32_16x16x32_bf16(aL, bH[ks][j], acc[i][j], 0, 0, 0);
        }
      }
    }
  }

  // ---- epilogue: C/D layout col=lane&15, row=quad*4+reg ----
#pragma unroll
  for (int i = 0; i < 4; ++i)
#pragma unroll
    for (int j = 0; j < 2; ++j) {
      const int col = n0 + wn + j * 16 + lm;
#pragma unroll
      for (int r = 0; r < 4; ++r) {
        const int row = m0 + wm + i * 16 + quad * 4 + r;
        if (row < M) {
          float v = acc[i][j][r];
          if (OMODE == 2) {
            int q = __float2int_rn(v * Q24_SCALE);
            q = q > 8388607 ? 8388607 : (q < -8388608 ? -8388608 : q);
            unsigned char* p = Cq + ((size_t)row * N + col) * 3;
            p[0] = (unsigned char)(q & 0xFF);
            p[1] = (unsigned char)((q >> 8) & 0xFF);
            p[2] = (unsigned char)((q >> 16) & 0xFF);
          } else {
            C[(size_t)row * N + col] = v;
          }
        }
      }
    }
#undef LOAD_TILE
#undef STORE_TILE
#undef SPLIT4W
}

// ---------------------------------------------------------------------------
// Original 256-thread split-bf16 MFMA GEMM (r11, known-good) — used for the
// two small head GEMMs (5/6) where A and B both come from fp32 on the fly.
// 128x128 tile, BK=64, 4 waves 2x2, launch_bounds(256,2).
// OMODE: 0 = fp32 C, 1 = sigmoid fp32 C.
// ---------------------------------------------------------------------------
template <int OMODE>
__global__ __launch_bounds__(256, 2) void gemm_mfma_split(
    const float* __restrict__ Af, const float* __restrict__ BTf,
    float* __restrict__ C, int M, int N, int K) {
  __shared__ unsigned short sAh[128 * LDSPAD];
  __shared__ unsigned short sAl[128 * LDSPAD];
  __shared__ unsigned short sBh[128 * LDSPAD];
  __shared__ unsigned short sBl[128 * LDSPAD];

  const int tid  = threadIdx.x;
  const int lane = tid & 63;
  const int wave = tid >> 6;
  const int wm   = (wave >> 1) << 6;
  const int wn   = (wave & 1) << 6;
  const int lm   = lane & 15;
  const int quad = lane >> 4;
  const int m0   = blockIdx.y * 128;
  const int n0   = blockIdx.x * 128;

  const int r32 = tid >> 4;            // 0..15
  const int c32 = (tid & 15) * 4;      // float4 col

  float4 pA[8];
  float4 pB[8];

  f32x4 acc[4][4];
#pragma unroll
  for (int i = 0; i < 4; ++i)
#pragma unroll
    for (int j = 0; j < 4; ++j)
#pragma unroll
      for (int r = 0; r < 4; ++r) acc[i][j][r] = 0.f;

#define LOAD_TILE(k0)                                                          \
  do {                                                                         \
    _Pragma("unroll") for (int p = 0; p < 8; ++p) {                            \
      const int m = m0 + p * 16 + r32;                                         \
      pA[p] = make_float4(0.f, 0.f, 0.f, 0.f);                                 \
      if (m < M) pA[p] = *(const float4*)&Af[(size_t)m * K + (k0) + c32];      \
    }                                                                          \
    _Pragma("unroll") for (int p = 0; p < 8; ++p) {                            \
      const int n = n0 + p * 16 + r32;                                         \
      pB[p] = *(const float4*)&BTf[(size_t)n * K + (k0) + c32];                \
    }                                                                          \
  } while (0)

#define SPLIT4(v, hv, lv)                                                      \
  hv.x = bf16_rn(v.x); lv.x = bf16_rn(v.x - bf16_to_f(hv.x));                  \
  hv.y = bf16_rn(v.y); lv.y = bf16_rn(v.y - bf16_to_f(hv.y));                  \
  hv.z = bf16_rn(v.z); lv.z = bf16_rn(v.z - bf16_to_f(hv.z));                  \
  hv.w = bf16_rn(v.w); lv.w = bf16_rn(v.w - bf16_to_f(hv.w));

#define STORE_TILE()                                                           \
  do {                                                                         \
    _Pragma("unroll") for (int p = 0; p < 8; ++p) {                            \
      ushort4 hv, lv; SPLIT4(pA[p], hv, lv);                                   \
      const int row = p * 16 + r32;                                            \
      *(ushort4*)&sAh[row * LDSPAD + c32] = hv;                                \
      *(ushort4*)&sAl[row * LDSPAD + c32] = lv;                                \
    }                                                                          \
    _Pragma("unroll") for (int p = 0; p < 8; ++p) {                            \
      ushort4 hv, lv; SPLIT4(pB[p], hv, lv);                                   \
      const int row = p * 16 + r32;                                            \
      *(ushort4*)&sBh[row * LDSPAD + c32] = hv;                                \
      *(ushort4*)&sBl[row * LDSPAD + c32] = lv;                                \
    }                                                                          \
  } while (0)

  LOAD_TILE(0);

  for (int k0 = 0; k0 < K; k0 += 64) {
    if (k0) __syncthreads();
    STORE_TILE();
    __syncthreads();
    if (k0 + 64 < K) LOAD_TILE(k0 + 64);

#pragma unroll
    for (int ks = 0; ks < 2; ++ks) {
      const int koff = ks * 32 + quad * 8;
      bf16x8 aH[4], aL[4], bH[4], bL[4];
#pragma unroll
      for (int i = 0; i < 4; ++i) {
        const int r = wm + i * 16 + lm;
        aH[i] = __builtin_bit_cast(bf16x8, *(const s16x8*)&sAh[r * LDSPAD + koff]);
        aL[i] = __builtin_bit_cast(bf16x8, *(const s16x8*)&sAl[r * LDSPAD + koff]);
      }
#pragma unroll
      for (int j = 0; j < 4; ++j) {
        const int r = wn + j * 16 + lm;
        bH[j] = __builtin_bit_cast(bf16x8, *(const s16x8*)&sBh[r * LDSPAD + koff]);
        bL[j] = __builtin_bit_cast(bf16x8, *(const s16x8*)&sBl[r * LDSPAD + koff]);
      }
#pragma unroll
      for (int i = 0; i < 4; ++i)
#pragma unroll
        for (int j = 0; j < 4; ++j) {
          acc[i][j] = __builtin_amdgcn_mfma_f32_16x16x32_bf16(aH[i], bH[j], acc[i][j], 0, 0, 0);
          acc[i][j] = __builtin_amdgcn_mfma_f32_16x16x32_bf16(aH[i], bL[j], acc[i][j], 0, 0, 0);
          acc[i][j] = __builtin_amdgcn_mfma_f32_16x16x32_bf16(aL[i], bH[j], acc[i][j], 0, 0, 0);
        }
    }
  }

#pragma unroll
  for (int i = 0; i < 4; ++i)
#pragma unroll
    for (int j = 0; j < 4; ++j) {
      const int col = n0 + wn + j * 16 + lm;
#pragma unroll
      for (int r = 0; r < 4; ++r) {
        const int row = m0 + wm + i * 16 + quad * 4 + r;
        if (row < M) {
          float v = acc[i][j][r];
          if (OMODE == 1) v = 1.f / (1.f + expf(-v));
          C[(size_t)row * N + col] = v;
        }
      }
    }
#undef LOAD_TILE
#undef STORE_TILE
#undef SPLIT4
}

// ---------------------------------------------------------------------------
// Fused prep: row_ptr build (edge-parallel) + W1/W2 transpose+split.
// ---------------------------------------------------------------------------
__global__ __launch_bounds__(256) void prep_all(
    const int* __restrict__ rows, int* __restrict__ row_ptr,
    const float* __restrict__ W1, unsigned short* __restrict__ W1Thi,
    unsigned short* __restrict__ W1Tlo,
    const float* __restrict__ W2, unsigned short* __restrict__ W2Thi,
    unsigned short* __restrict__ W2Tlo) {
  const int idx = blockIdx.x * 256 + threadIdx.x;
  if (idx < N_EDGES) {
    const int r = rows[idx];
    const int rprev = (idx == 0) ? -1 : rows[idx - 1];
    for (int n = rprev + 1; n <= r; ++n) row_ptr[n] = idx;
    if (idx == N_EDGES - 1)
      for (int n = r + 1; n <= N_NODES; ++n) row_ptr[n] = N_EDGES;
  }
  if (idx < NFEAT * NHID) {   // W1T[n*K+k] = split(W1[k*N+n]), K=NFEAT N=NHID
    const int n = idx / NFEAT;
    const int k = idx - n * NFEAT;
    const float f = W1[(size_t)k * NHID + n];
    const unsigned short h = bf16_rn(f);
    W1Thi[idx] = h;
    W1Tlo[idx] = bf16_rn(f - bf16_to_f(h));
  }
  if (idx < NHID * NCLASS) {  // W2T, K=NHID N=NCLASS
    const int n = idx / NHID;
    const int k = idx - n * NHID;
    const float f = W2[(size_t)k * NCLASS + n];
    const unsigned short h = bf16_rn(f);
    W2Thi[idx] = h;
    W2Tlo[idx] = bf16_rn(f - bf16_to_f(h));
  }
}

// ---------------------------------------------------------------------------
// SpMM F=256, interleaved q24 source (768B rows): one wave per node, lane =
// 12B dwordx3 = 4 elems (full row per wave). fp32 accumulate.
// 16-edge MASKED batches (r11). Fused bias+relu+bf16 hi/lo split output.
// ---------------------------------------------------------------------------
__global__ __launch_bounds__(256, 4) void spmm256_q24_split(
    const unsigned char* __restrict__ Sq, const int* __restrict__ row_ptr,
    const int* __restrict__ cols, const float* __restrict__ vals,
    const float4* __restrict__ bias4,
    unsigned short* __restrict__ outHi, unsigned short* __restrict__ outLo) {
  const int wave = threadIdx.x >> 6;
  const int lane = threadIdx.x & 63;
  const int node = blockIdx.x * 4 + wave;

  // lo/hi are wave-uniform (node is): pin to SGPRs for scalar loop control
  const int lou = __builtin_amdgcn_readfirstlane(row_ptr[node]);
  const int hiu = __builtin_amdgcn_readfirstlane(row_ptr[node + 1]);

  float4 acc = make_float4(0.f, 0.f, 0.f, 0.f);
  const int lane12 = lane * 12;

  for (int base = lou; base < hiu; base += 16) {
    int   c[16];
    float w[16];   // pre-scaled by Q24_INV; 0 for masked slots
    if (base + 16 <= hiu) {           // full batch: unclamped contiguous loads
#pragma unroll
      for (int t = 0; t < 16; ++t) {
        c[t] = cols[base + t];
        w[t] = vals[base + t] * Q24_INV;
      }
    } else {                          // final partial batch: clamp+mask
#pragma unroll
      for (int t = 0; t < 16; ++t) {
        const int idx = base + t;
        const int ide = idx < hiu ? idx : hiu - 1;   // valid duplicate row
        c[t] = cols[ide];
        w[t] = idx < hiu ? vals[ide] * Q24_INV : 0.f;
      }
    }
    U3 d[16];
#pragma unroll
    for (int t = 0; t < 16; ++t)
      d[t] = *(const U3*)&Sq[(size_t)c[t] * (NHID * 3) + lane12];
#pragma unroll
    for (int t = 0; t < 16; ++t) {
      int e0, e1, e2, e3;
      unpack24(d[t].a, d[t].b, d[t].c, e0, e1, e2, e3);
      acc.x = fmaf(w[t], (float)e0, acc.x);
      acc.y = fmaf(w[t], (float)e1, acc.y);
      acc.z = fmaf(w[t], (float)e2, acc.z);
      acc.w = fmaf(w[t], (float)e3, acc.w);
    }
  }

  const float4 b = bias4[lane];
  acc.x = fmaxf(acc.x + b.x, 0.f);
  acc.y = fmaxf(acc.y + b.y, 0.f);
  acc.z = fmaxf(acc.z + b.z, 0.f);
  acc.w = fmaxf(acc.w + b.w, 0.f);

  ushort4 hv, lv;
  hv.x = bf16_rn(acc.x); lv.x = bf16_rn(acc.x - bf16_to_f(hv.x));
  hv.y = bf16_rn(acc.y); lv.y = bf16_rn(acc.y - bf16_to_f(hv.y));
  hv.z = bf16_rn(acc.z); lv.z = bf16_rn(acc.z - bf16_to_f(hv.z));
  hv.w = bf16_rn(acc.w); lv.w = bf16_rn(acc.w - bf16_to_f(hv.w));
  const size_t o = (size_t)node * NHID + lane * 4;
  *(ushort4*)&outHi[o] = hv;
  *(ushort4*)&outLo[o] = lv;
}

// ---------------------------------------------------------------------------
// SpMM F=128 over the 4096 LISTED nodes only (concat(u,v)) — Z is consumed
// only at rows u,v. One wave per list entry; half-waves alternate edges
// (32 lanes x float4 = full 512B row), 4-edge unroll per half. fp32 out ZUV.
// ---------------------------------------------------------------------------
__global__ __launch_bounds__(256) void spmm128_f32_list(
    const float4* __restrict__ S4, const int* __restrict__ row_ptr,
    const int* __restrict__ cols, const float* __restrict__ vals,
    const float4* __restrict__ bias4,
    const int* __restrict__ u, const int* __restrict__ v,
    float4* __restrict__ out4) {
  const int wave = threadIdx.x >> 6;
  const int lane = threadIdx.x & 63;
  const int half = lane >> 5;
  const int l32  = lane & 31;
  const int idx  = blockIdx.x * 4 + wave;          // 0..4095
  const int node = idx < N_UV ? u[idx] : v[idx - N_UV];

  const int lo = row_ptr[node];
  const int hi = row_ptr[node + 1];

  float4 acc = make_float4(0.f, 0.f, 0.f, 0.f);
  int e = lo + half;
  for (; e + 6 < hi; e += 8) {   // edges e, e+2, e+4, e+6 for this half
    int c[4]; float w[4];
#pragma unroll
    for (int t = 0; t < 4; ++t) { c[t] = cols[e + 2 * t]; w[t] = vals[e + 2 * t]; }
    float4 r[4];
#pragma unroll
    for (int t = 0; t < 4; ++t) r[t] = S4[(size_t)c[t] * 32 + l32];
#pragma unroll
    for (int t = 0; t < 4; ++t) {
      acc.x = fmaf(w[t], r[t].x, acc.x); acc.y = fmaf(w[t], r[t].y, acc.y);
      acc.z = fmaf(w[t], r[t].z, acc.z); acc.w = fmaf(w[t], r[t].w, acc.w);
    }
  }
  for (; e < hi; e += 2) {
    const int c = cols[e];
    const float w = vals[e];
    const float4 r = S4[(size_t)c * 32 + l32];
    acc.x = fmaf(w, r.x, acc.x); acc.y = fmaf(w, r.y, acc.y);
    acc.z = fmaf(w, r.z, acc.z); acc.w = fmaf(w, r.w, acc.w);
  }

  acc.x += __shfl_xor(acc.x, 32);
  acc.y += __shfl_xor(acc.y, 32);
  acc.z += __shfl_xor(acc.z, 32);
  acc.w += __shfl_xor(acc.w, 32);

  if (half == 0) {
    const float4 b = bias4[l32];
    acc.x += b.x; acc.y += b.y; acc.z += b.z; acc.w += b.w;
    out4[(size_t)idx * 32 + l32] = acc;
  }
}

// ---------------------------------------------------------------------------
// Launch
// ---------------------------------------------------------------------------
extern "C" void kernel_launch(void* const* d_in, const int* in_sizes, int n_in,
                              void* d_out, int out_size, void* d_ws, size_t ws_size,
                              hipStream_t stream) {
  const int*   u       = (const int*)  d_in[0];
  const int*   v       = (const int*)  d_in[1];
  const float* x       = (const float*)d_in[2];
  const int*   adj_row = (const int*)  d_in[3];
  const int*   adj_col = (const int*)  d_in[4];
  const float* adj_val = (const float*)d_in[5];
  const float* W1      = (const float*)d_in[6];
  const float* b1      = (const float*)d_in[7];
  const float* W2      = (const float*)d_in[8];
  const float* b2      = (const float*)d_in[9];
  const float* We      = (const float*)d_in[10];
  float* out = (float*)d_out;

  char* wsb = (char*)d_ws;
  // Region A [0, 51.2MB):
  //   S1q interleaved q24 38.4MB at [0, 38.4MB)
  //   after spmm1: S2 fp32 [0, 25.6MB), ZUV fp32 [25.6, 27.7MB)
  unsigned char* S1q = (unsigned char*)wsb;
  float* S2  = (float*)wsb;
  float* ZUV = (float*)(wsb + (size_t)N_NODES * NCLASS * sizeof(float));
  // Region B [51.2MB, 102.4MB): Hhi/Hlo; after GEMM2 dead -> ZU
  char* rB = wsb + (size_t)N_NODES * NHID * sizeof(float);
  unsigned short* Hhi = (unsigned short*)rB;
  unsigned short* Hlo = Hhi + (size_t)N_NODES * NHID;
  float* ZU = (float*)rB;                  // 2048*128
  // Split weights + row_ptr parked in d_out (dead until the final GEMM)
  unsigned short* W1Thi = (unsigned short*)out;
  unsigned short* W1Tlo = W1Thi + NHID * NFEAT;
  unsigned short* W2Thi = W1Tlo + NHID * NFEAT;
  unsigned short* W2Tlo = W2Thi + NCLASS * NHID;
  int* row_ptr = (int*)(W2Tlo + NCLASS * NHID);   // 50001 ints

  // 0) fused prep: row_ptr + weight transpose/split (one launch)
  prep_all<<<(N_EDGES + 255) / 256, 256, 0, stream>>>(
      adj_row, row_ptr, W1, W1Thi, W1Tlo, W2, W2Thi, W2Tlo);

  // 1) S1q = q24(x @ W1)  (wide MFMA, A split on the fly, B direct)
  gemm_mfma_wide<true, 2>
      <<<dim3(NHID / 128, (N_NODES + 127) / 128), 512, 0, stream>>>(
      x, nullptr, nullptr, W1Thi, W1Tlo,
      nullptr, S1q, N_NODES, NHID, NFEAT);

  // 2) Hhi/Hlo = split(relu(A @ S1 + b1))   (interleaved q24 gather)
  spmm256_q24_split<<<N_NODES / 4, 256, 0, stream>>>(
      S1q, row_ptr, adj_col, adj_val, (const float4*)b1, Hhi, Hlo);

  // 3) S2 = H @ W2  (wide MFMA, A pre-split, B direct, fp32 out)
  gemm_mfma_wide<false, 0>
      <<<dim3(NCLASS / 128, (N_NODES + 127) / 128), 512, 0, stream>>>(
      nullptr, Hhi, Hlo, W2Thi, W2Tlo,
      S2, nullptr, N_NODES, NCLASS, NHID);

  // 4) ZUV = (A @ S2 + b2)[concat(u,v)]  — only the 4096 rows the head uses
  spmm128_f32_list<<<(2 * N_UV) / 4, 256, 0, stream>>>(
      (const float4*)S2, row_ptr, adj_col, adj_val, (const float4*)b2,
      u, v, (float4*)ZUV);

  // 5) ZU = ZUV[0:2048] @ We^T  (BT = We as stored)
  gemm_mfma_split<0>
      <<<dim3(NCLASS / 128, N_UV / 128), 256, 0, stream>>>(
      ZUV, We, ZU, N_UV, NCLASS, NCLASS);

  // 6) out = sigmoid(ZU @ ZUV[2048:4096]^T)
  gemm_mfma_split<1>
      <<<dim3(N_UV / 128, N_UV / 128), 256, 0, stream>>>(
      ZU, ZUV + (size_t)N_UV * NCLASS, out, N_UV, N_UV, NCLASS);
}

// Round 6
// 370.250 us; speedup vs baseline: 1.6414x; 1.0408x over previous
//
#include <hip/hip_runtime.h>
#include <hip/hip_bf16.h>
#include <math.h>

// ---------------------------------------------------------------------------
// Problem constants (from reference)
// ---------------------------------------------------------------------------
#define N_NODES 50000
#define N_EDGES 800000
#define NFEAT   512
#define NHID    256
#define NCLASS  128
#define N_UV    2048

// q24 fixed-point: scale 2^19, range +-16 (|S1|<~5 -> wide margin)
#define Q24_SCALE  524288.0f
#define Q24_INV    1.9073486328125e-6f

typedef __bf16    bf16x8 __attribute__((ext_vector_type(8)));
typedef short     s16x8  __attribute__((ext_vector_type(8)));
typedef float     f32x4  __attribute__((ext_vector_type(4)));

struct __attribute__((packed)) U3 { unsigned a, b, c; };  // 12B dwordx3 view

__device__ __forceinline__ unsigned short bf16_rn(float f) {
  unsigned u = __float_as_uint(f);
  u += 0x7fffu + ((u >> 16) & 1u);
  return (unsigned short)(u >> 16);
}
__device__ __forceinline__ float bf16_to_f(unsigned short h) {
  return __uint_as_float(((unsigned)h) << 16);
}
// 4 x 24-bit signed little-endian values from 3 dwords
__device__ __forceinline__ void unpack24(unsigned a, unsigned b, unsigned c,
                                         int& e0, int& e1, int& e2, int& e3) {
  e0 = ((int)(a << 8)) >> 8;
  e1 = ((int)((b << 16) | ((a >> 24) << 8))) >> 8;
  e2 = ((int)((c << 24) | ((b >> 16) << 8))) >> 8;
  e3 = ((int)c) >> 8;
}

#define LDSPAD 72   // 64 + 8 shorts: keeps 16B alignment, breaks pow2 stride

// ---------------------------------------------------------------------------
// WIDE GEMM for the two big N_NODES-row GEMMs: C[M,N] = A[M,K] @ BT[N,K]^T
// split-bf16 3-term (Ahi*Bhi + Ahi*Blo + Alo*Bhi).
//
// r16: BM=64 / 256-thr / 4 waves (1M x 4N, per-wave 64x32, acc 4x2 = 32
// AGPR — same per-wave shape as r13). Grid doubles to 1564 blocks; LDS
// 18.4KB and VGPR ~110 under (256,4) -> 4 RESIDENT BLOCKS/CU.
// Rationale: r13/r14 counters (Mfma 13.5, VALU 18.5, hbm 15%, dur 117us
// vs ~22us mem floor) = stall-dominated. The barrier-locked K-loop drains
// vmcnt(0) 2x/tile and with only 2-3 blocks/CU there is no independent
// work to cover the drains. More waves in-block (r13) hit the same
// barrier together; more independent BLOCKS/CU is the lever.
// B read DIRECT from global (W1/W2 hi+lo 512KB/128KB, L2-resident),
// hoisted before the A prefetch (r14, neutral but harmless).
// ---------------------------------------------------------------------------
template <bool ASPLIT, int OMODE>
__global__ __launch_bounds__(256, 4) void gemm_mfma_wide(
    const float* __restrict__ Af,
    const unsigned short* __restrict__ Ahi, const unsigned short* __restrict__ Alo,
    const unsigned short* __restrict__ BThi, const unsigned short* __restrict__ BTlo,
    float* __restrict__ C, unsigned char* __restrict__ Cq, int M, int N, int K) {
  __shared__ unsigned short sAh[64 * LDSPAD];
  __shared__ unsigned short sAl[64 * LDSPAD];

  const int tid  = threadIdx.x;
  const int lane = tid & 63;
  const int wave = tid >> 6;           // 0..3
  const int wn   = wave << 5;          // 0,32,64,96
  const int lm   = lane & 15;
  const int quad = lane >> 4;
  const int m0   = blockIdx.y * 64;
  const int n0   = blockIdx.x * 128;

  // staging coordinates (BK=64, 256 threads, 64 rows)
  const int r32 = tid >> 4;            // 0..15 (fp32: 16 rows/pass, 4 passes)
  const int c32 = (tid & 15) * 4;      // float4 col
  const int r16 = tid >> 3;            // 0..31 (bf16: 32 rows/pass, 2 passes)
  const int c16 = (tid & 7) * 8;       // s16x8 col

  float4 pA[4]; s16x8 pAh[2], pAl[2];

  f32x4 acc[4][2];
#pragma unroll
  for (int i = 0; i < 4; ++i)
#pragma unroll
    for (int j = 0; j < 2; ++j)
#pragma unroll
      for (int r = 0; r < 4; ++r) acc[i][j][r] = 0.f;

#define LOAD_TILE(k0)                                                          \
  do {                                                                         \
    if (ASPLIT) {                                                              \
      _Pragma("unroll") for (int p = 0; p < 4; ++p) {                          \
        const int m = m0 + p * 16 + r32;                                       \
        pA[p] = make_float4(0.f, 0.f, 0.f, 0.f);                               \
        if (m < M) pA[p] = *(const float4*)&Af[(size_t)m * K + (k0) + c32];    \
      }                                                                        \
    } else {                                                                   \
      _Pragma("unroll") for (int p = 0; p < 2; ++p) {                          \
        const int m = m0 + p * 32 + r16;                                       \
        _Pragma("unroll") for (int e = 0; e < 8; ++e) { pAh[p][e] = 0; pAl[p][e] = 0; } \
        if (m < M) {                                                           \
          pAh[p] = *(const s16x8*)&Ahi[(size_t)m * K + (k0) + c16];            \
          pAl[p] = *(const s16x8*)&Alo[(size_t)m * K + (k0) + c16];            \
        }                                                                      \
      }                                                                        \
    }                                                                          \
  } while (0)

#define SPLIT4W(v, hv, lv)                                                     \
  hv.x = bf16_rn(v.x); lv.x = bf16_rn(v.x - bf16_to_f(hv.x));                  \
  hv.y = bf16_rn(v.y); lv.y = bf16_rn(v.y - bf16_to_f(hv.y));                  \
  hv.z = bf16_rn(v.z); lv.z = bf16_rn(v.z - bf16_to_f(hv.z));                  \
  hv.w = bf16_rn(v.w); lv.w = bf16_rn(v.w - bf16_to_f(hv.w));

#define STORE_TILE()                                                           \
  do {                                                                         \
    if (ASPLIT) {                                                              \
      _Pragma("unroll") for (int p = 0; p < 4; ++p) {                          \
        ushort4 hv, lv; SPLIT4W(pA[p], hv, lv);                                \
        const int row = p * 16 + r32;                                          \
        *(ushort4*)&sAh[row * LDSPAD + c32] = hv;                              \
        *(ushort4*)&sAl[row * LDSPAD + c32] = lv;                              \
      }                                                                        \
    } else {                                                                   \
      _Pragma("unroll") for (int p = 0; p < 2; ++p) {                          \
        const int row = p * 32 + r16;                                          \
        *(s16x8*)&sAh[row * LDSPAD + c16] = pAh[p];                            \
        *(s16x8*)&sAl[row * LDSPAD + c16] = pAl[p];                            \
      }                                                                        \
    }                                                                          \
  } while (0)

  LOAD_TILE(0);

  // B fragment row bases (direct-from-global, L2-resident weights)
  const unsigned short* Bhrow = BThi + (size_t)(n0 + wn + lm) * K;
  const unsigned short* Blrow = BTlo + (size_t)(n0 + wn + lm) * K;

  for (int k0 = 0; k0 < K; k0 += 64) {
    if (k0) __syncthreads();      // WAR: prior iter's frag reads complete
    STORE_TILE();
    __syncthreads();              // RAW: stores visible

    // B fragments for THIS K-tile, issued BEFORE the A prefetch (r14).
    bf16x8 bH[2][2], bL[2][2];
#pragma unroll
    for (int ks = 0; ks < 2; ++ks)
#pragma unroll
      for (int j = 0; j < 2; ++j) {
        const size_t off = (size_t)(j * 16) * K + k0 + ks * 32 + quad * 8;
        bH[ks][j] = __builtin_bit_cast(bf16x8, *(const s16x8*)(Bhrow + off));
        bL[ks][j] = __builtin_bit_cast(bf16x8, *(const s16x8*)(Blrow + off));
      }

    if (k0 + 64 < K) LOAD_TILE(k0 + 64);   // prefetch next tile (newest vmem)

#pragma unroll
    for (int ks = 0; ks < 2; ++ks) {
      const int koff = ks * 32 + quad * 8;
#pragma unroll
      for (int i = 0; i < 4; ++i) {
        const int r = i * 16 + lm;
        const bf16x8 aH = __builtin_bit_cast(bf16x8, *(const s16x8*)&sAh[r * LDSPAD + koff]);
        const bf16x8 aL = __builtin_bit_cast(bf16x8, *(const s16x8*)&sAl[r * LDSPAD + koff]);
#pragma unroll
        for (int j = 0; j < 2; ++j) {
          acc[i][j] = __builtin_amdgcn_mfma_f32_16x16x32_bf16(aH, bH[ks][j], acc[i][j], 0, 0, 0);
          acc[i][j] = __builtin_amdgcn_mfma_f32_16x16x32_bf16(aH, bL[ks][j], acc[i][j], 0, 0, 0);
          acc[i][j] = __builtin_amdgcn_mfma_f32_16x16x32_bf16(aL, bH[ks][j], acc[i][j], 0, 0, 0);
        }
      }
    }
  }

  // ---- epilogue: C/D layout col=lane&15, row=quad*4+reg ----
#pragma unroll
  for (int i = 0; i < 4; ++i)
#pragma unroll
    for (int j = 0; j < 2; ++j) {
      const int col = n0 + wn + j * 16 + lm;
#pragma unroll
      for (int r = 0; r < 4; ++r) {
        const int row = m0 + i * 16 + quad * 4 + r;
        if (row < M) {
          float v = acc[i][j][r];
          if (OMODE == 2) {
            int q = __float2int_rn(v * Q24_SCALE);
            q = q > 8388607 ? 8388607 : (q < -8388608 ? -8388608 : q);
            unsigned char* p = Cq + ((size_t)row * N + col) * 3;
            p[0] = (unsigned char)(q & 0xFF);
            p[1] = (unsigned char)((q >> 8) & 0xFF);
            p[2] = (unsigned char)((q >> 16) & 0xFF);
          } else {
            C[(size_t)row * N + col] = v;
          }
        }
      }
    }
#undef LOAD_TILE
#undef STORE_TILE
#undef SPLIT4W
}

// ---------------------------------------------------------------------------
// Original 256-thread split-bf16 MFMA GEMM (r11, known-good) — used for the
// two small head GEMMs (5/6) where A and B both come from fp32 on the fly.
// 128x128 tile, BK=64, 4 waves 2x2, launch_bounds(256,2).
// OMODE: 0 = fp32 C, 1 = sigmoid fp32 C.
// ---------------------------------------------------------------------------
template <int OMODE>
__global__ __launch_bounds__(256, 2) void gemm_mfma_split(
    const float* __restrict__ Af, const float* __restrict__ BTf,
    float* __restrict__ C, int M, int N, int K) {
  __shared__ unsigned short sAh[128 * LDSPAD];
  __shared__ unsigned short sAl[128 * LDSPAD];
  __shared__ unsigned short sBh[128 * LDSPAD];
  __shared__ unsigned short sBl[128 * LDSPAD];

  const int tid  = threadIdx.x;
  const int lane = tid & 63;
  const int wave = tid >> 6;
  const int wm   = (wave >> 1) << 6;
  const int wn   = (wave & 1) << 6;
  const int lm   = lane & 15;
  const int quad = lane >> 4;
  const int m0   = blockIdx.y * 128;
  const int n0   = blockIdx.x * 128;

  const int r32 = tid >> 4;            // 0..15
  const int c32 = (tid & 15) * 4;      // float4 col

  float4 pA[8];
  float4 pB[8];

  f32x4 acc[4][4];
#pragma unroll
  for (int i = 0; i < 4; ++i)
#pragma unroll
    for (int j = 0; j < 4; ++j)
#pragma unroll
      for (int r = 0; r < 4; ++r) acc[i][j][r] = 0.f;

#define LOAD_TILE(k0)                                                          \
  do {                                                                         \
    _Pragma("unroll") for (int p = 0; p < 8; ++p) {                            \
      const int m = m0 + p * 16 + r32;                                         \
      pA[p] = make_float4(0.f, 0.f, 0.f, 0.f);                                 \
      if (m < M) pA[p] = *(const float4*)&Af[(size_t)m * K + (k0) + c32];      \
    }                                                                          \
    _Pragma("unroll") for (int p = 0; p < 8; ++p) {                            \
      const int n = n0 + p * 16 + r32;                                         \
      pB[p] = *(const float4*)&BTf[(size_t)n * K + (k0) + c32];                \
    }                                                                          \
  } while (0)

#define SPLIT4(v, hv, lv)                                                      \
  hv.x = bf16_rn(v.x); lv.x = bf16_rn(v.x - bf16_to_f(hv.x));                  \
  hv.y = bf16_rn(v.y); lv.y = bf16_rn(v.y - bf16_to_f(hv.y));                  \
  hv.z = bf16_rn(v.z); lv.z = bf16_rn(v.z - bf16_to_f(hv.z));                  \
  hv.w = bf16_rn(v.w); lv.w = bf16_rn(v.w - bf16_to_f(hv.w));

#define STORE_TILE()                                                           \
  do {                                                                         \
    _Pragma("unroll") for (int p = 0; p < 8; ++p) {                            \
      ushort4 hv, lv; SPLIT4(pA[p], hv, lv);                                   \
      const int row = p * 16 + r32;                                            \
      *(ushort4*)&sAh[row * LDSPAD + c32] = hv;                                \
      *(ushort4*)&sAl[row * LDSPAD + c32] = lv;                                \
    }                                                                          \
    _Pragma("unroll") for (int p = 0; p < 8; ++p) {                            \
      ushort4 hv, lv; SPLIT4(pB[p], hv, lv);                                   \
      const int row = p * 16 + r32;                                            \
      *(ushort4*)&sBh[row * LDSPAD + c32] = hv;                                \
      *(ushort4*)&sBl[row * LDSPAD + c32] = lv;                                \
    }                                                                          \
  } while (0)

  LOAD_TILE(0);

  for (int k0 = 0; k0 < K; k0 += 64) {
    if (k0) __syncthreads();
    STORE_TILE();
    __syncthreads();
    if (k0 + 64 < K) LOAD_TILE(k0 + 64);

#pragma unroll
    for (int ks = 0; ks < 2; ++ks) {
      const int koff = ks * 32 + quad * 8;
      bf16x8 aH[4], aL[4], bH[4], bL[4];
#pragma unroll
      for (int i = 0; i < 4; ++i) {
        const int r = wm + i * 16 + lm;
        aH[i] = __builtin_bit_cast(bf16x8, *(const s16x8*)&sAh[r * LDSPAD + koff]);
        aL[i] = __builtin_bit_cast(bf16x8, *(const s16x8*)&sAl[r * LDSPAD + koff]);
      }
#pragma unroll
      for (int j = 0; j < 4; ++j) {
        const int r = wn + j * 16 + lm;
        bH[j] = __builtin_bit_cast(bf16x8, *(const s16x8*)&sBh[r * LDSPAD + koff]);
        bL[j] = __builtin_bit_cast(bf16x8, *(const s16x8*)&sBl[r * LDSPAD + koff]);
      }
#pragma unroll
      for (int i = 0; i < 4; ++i)
#pragma unroll
        for (int j = 0; j < 4; ++j) {
          acc[i][j] = __builtin_amdgcn_mfma_f32_16x16x32_bf16(aH[i], bH[j], acc[i][j], 0, 0, 0);
          acc[i][j] = __builtin_amdgcn_mfma_f32_16x16x32_bf16(aH[i], bL[j], acc[i][j], 0, 0, 0);
          acc[i][j] = __builtin_amdgcn_mfma_f32_16x16x32_bf16(aL[i], bH[j], acc[i][j], 0, 0, 0);
        }
    }
  }

#pragma unroll
  for (int i = 0; i < 4; ++i)
#pragma unroll
    for (int j = 0; j < 4; ++j) {
      const int col = n0 + wn + j * 16 + lm;
#pragma unroll
      for (int r = 0; r < 4; ++r) {
        const int row = m0 + wm + i * 16 + quad * 4 + r;
        if (row < M) {
          float v = acc[i][j][r];
          if (OMODE == 1) v = 1.f / (1.f + expf(-v));
          C[(size_t)row * N + col] = v;
        }
      }
    }
#undef LOAD_TILE
#undef STORE_TILE
#undef SPLIT4
}

// ---------------------------------------------------------------------------
// Fused prep: row_ptr build (edge-parallel) + W1/W2 transpose+split.
// ---------------------------------------------------------------------------
__global__ __launch_bounds__(256) void prep_all(
    const int* __restrict__ rows, int* __restrict__ row_ptr,
    const float* __restrict__ W1, unsigned short* __restrict__ W1Thi,
    unsigned short* __restrict__ W1Tlo,
    const float* __restrict__ W2, unsigned short* __restrict__ W2Thi,
    unsigned short* __restrict__ W2Tlo) {
  const int idx = blockIdx.x * 256 + threadIdx.x;
  if (idx < N_EDGES) {
    const int r = rows[idx];
    const int rprev = (idx == 0) ? -1 : rows[idx - 1];
    for (int n = rprev + 1; n <= r; ++n) row_ptr[n] = idx;
    if (idx == N_EDGES - 1)
      for (int n = r + 1; n <= N_NODES; ++n) row_ptr[n] = N_EDGES;
  }
  if (idx < NFEAT * NHID) {   // W1T[n*K+k] = split(W1[k*N+n]), K=NFEAT N=NHID
    const int n = idx / NFEAT;
    const int k = idx - n * NFEAT;
    const float f = W1[(size_t)k * NHID + n];
    const unsigned short h = bf16_rn(f);
    W1Thi[idx] = h;
    W1Tlo[idx] = bf16_rn(f - bf16_to_f(h));
  }
  if (idx < NHID * NCLASS) {  // W2T, K=NHID N=NCLASS
    const int n = idx / NHID;
    const int k = idx - n * NHID;
    const float f = W2[(size_t)k * NCLASS + n];
    const unsigned short h = bf16_rn(f);
    W2Thi[idx] = h;
    W2Tlo[idx] = bf16_rn(f - bf16_to_f(h));
  }
}

// ---------------------------------------------------------------------------
// SpMM F=256, interleaved q24 source (768B rows): one wave per node, lane =
// 12B dwordx3 = 4 elems (full row per wave). fp32 accumulate.
// 16-edge MASKED batches (r11). Fused bias+relu+bf16 hi/lo split output.
// ---------------------------------------------------------------------------
__global__ __launch_bounds__(256, 4) void spmm256_q24_split(
    const unsigned char* __restrict__ Sq, const int* __restrict__ row_ptr,
    const int* __restrict__ cols, const float* __restrict__ vals,
    const float4* __restrict__ bias4,
    unsigned short* __restrict__ outHi, unsigned short* __restrict__ outLo) {
  const int wave = threadIdx.x >> 6;
  const int lane = threadIdx.x & 63;
  const int node = blockIdx.x * 4 + wave;

  // lo/hi are wave-uniform (node is): pin to SGPRs for scalar loop control
  const int lou = __builtin_amdgcn_readfirstlane(row_ptr[node]);
  const int hiu = __builtin_amdgcn_readfirstlane(row_ptr[node + 1]);

  float4 acc = make_float4(0.f, 0.f, 0.f, 0.f);
  const int lane12 = lane * 12;

  for (int base = lou; base < hiu; base += 16) {
    int   c[16];
    float w[16];   // pre-scaled by Q24_INV; 0 for masked slots
    if (base + 16 <= hiu) {           // full batch: unclamped contiguous loads
#pragma unroll
      for (int t = 0; t < 16; ++t) {
        c[t] = cols[base + t];
        w[t] = vals[base + t] * Q24_INV;
      }
    } else {                          // final partial batch: clamp+mask
#pragma unroll
      for (int t = 0; t < 16; ++t) {
        const int idx = base + t;
        const int ide = idx < hiu ? idx : hiu - 1;   // valid duplicate row
        c[t] = cols[ide];
        w[t] = idx < hiu ? vals[ide] * Q24_INV : 0.f;
      }
    }
    U3 d[16];
#pragma unroll
    for (int t = 0; t < 16; ++t)
      d[t] = *(const U3*)&Sq[(size_t)c[t] * (NHID * 3) + lane12];
#pragma unroll
    for (int t = 0; t < 16; ++t) {
      int e0, e1, e2, e3;
      unpack24(d[t].a, d[t].b, d[t].c, e0, e1, e2, e3);
      acc.x = fmaf(w[t], (float)e0, acc.x);
      acc.y = fmaf(w[t], (float)e1, acc.y);
      acc.z = fmaf(w[t], (float)e2, acc.z);
      acc.w = fmaf(w[t], (float)e3, acc.w);
    }
  }

  const float4 b = bias4[lane];
  acc.x = fmaxf(acc.x + b.x, 0.f);
  acc.y = fmaxf(acc.y + b.y, 0.f);
  acc.z = fmaxf(acc.z + b.z, 0.f);
  acc.w = fmaxf(acc.w + b.w, 0.f);

  ushort4 hv, lv;
  hv.x = bf16_rn(acc.x); lv.x = bf16_rn(acc.x - bf16_to_f(hv.x));
  hv.y = bf16_rn(acc.y); lv.y = bf16_rn(acc.y - bf16_to_f(hv.y));
  hv.z = bf16_rn(acc.z); lv.z = bf16_rn(acc.z - bf16_to_f(hv.z));
  hv.w = bf16_rn(acc.w); lv.w = bf16_rn(acc.w - bf16_to_f(hv.w));
  const size_t o = (size_t)node * NHID + lane * 4;
  *(ushort4*)&outHi[o] = hv;
  *(ushort4*)&outLo[o] = lv;
}

// ---------------------------------------------------------------------------
// SpMM F=128 over the 4096 LISTED nodes only (concat(u,v)) — Z is consumed
// only at rows u,v. One wave per list entry; half-waves alternate edges
// (32 lanes x float4 = full 512B row), 4-edge unroll per half. fp32 out ZUV.
// ---------------------------------------------------------------------------
__global__ __launch_bounds__(256) void spmm128_f32_list(
    const float4* __restrict__ S4, const int* __restrict__ row_ptr,
    const int* __restrict__ cols, const float* __restrict__ vals,
    const float4* __restrict__ bias4,
    const int* __restrict__ u, const int* __restrict__ v,
    float4* __restrict__ out4) {
  const int wave = threadIdx.x >> 6;
  const int lane = threadIdx.x & 63;
  const int half = lane >> 5;
  const int l32  = lane & 31;
  const int idx  = blockIdx.x * 4 + wave;          // 0..4095
  const int node = idx < N_UV ? u[idx] : v[idx - N_UV];

  const int lo = row_ptr[node];
  const int hi = row_ptr[node + 1];

  float4 acc = make_float4(0.f, 0.f, 0.f, 0.f);
  int e = lo + half;
  for (; e + 6 < hi; e += 8) {   // edges e, e+2, e+4, e+6 for this half
    int c[4]; float w[4];
#pragma unroll
    for (int t = 0; t < 4; ++t) { c[t] = cols[e + 2 * t]; w[t] = vals[e + 2 * t]; }
    float4 r[4];
#pragma unroll
    for (int t = 0; t < 4; ++t) r[t] = S4[(size_t)c[t] * 32 + l32];
#pragma unroll
    for (int t = 0; t < 4; ++t) {
      acc.x = fmaf(w[t], r[t].x, acc.x); acc.y = fmaf(w[t], r[t].y, acc.y);
      acc.z = fmaf(w[t], r[t].z, acc.z); acc.w = fmaf(w[t], r[t].w, acc.w);
    }
  }
  for (; e < hi; e += 2) {
    const int c = cols[e];
    const float w = vals[e];
    const float4 r = S4[(size_t)c * 32 + l32];
    acc.x = fmaf(w, r.x, acc.x); acc.y = fmaf(w, r.y, acc.y);
    acc.z = fmaf(w, r.z, acc.z); acc.w = fmaf(w, r.w, acc.w);
  }

  acc.x += __shfl_xor(acc.x, 32);
  acc.y += __shfl_xor(acc.y, 32);
  acc.z += __shfl_xor(acc.z, 32);
  acc.w += __shfl_xor(acc.w, 32);

  if (half == 0) {
    const float4 b = bias4[l32];
    acc.x += b.x; acc.y += b.y; acc.z += b.z; acc.w += b.w;
    out4[(size_t)idx * 32 + l32] = acc;
  }
}

// ---------------------------------------------------------------------------
// Launch
// ---------------------------------------------------------------------------
extern "C" void kernel_launch(void* const* d_in, const int* in_sizes, int n_in,
                              void* d_out, int out_size, void* d_ws, size_t ws_size,
                              hipStream_t stream) {
  const int*   u       = (const int*)  d_in[0];
  const int*   v       = (const int*)  d_in[1];
  const float* x       = (const float*)d_in[2];
  const int*   adj_row = (const int*)  d_in[3];
  const int*   adj_col = (const int*)  d_in[4];
  const float* adj_val = (const float*)d_in[5];
  const float* W1      = (const float*)d_in[6];
  const float* b1      = (const float*)d_in[7];
  const float* W2      = (const float*)d_in[8];
  const float* b2      = (const float*)d_in[9];
  const float* We      = (const float*)d_in[10];
  float* out = (float*)d_out;

  char* wsb = (char*)d_ws;
  // Region A [0, 51.2MB):
  //   S1q interleaved q24 38.4MB at [0, 38.4MB)
  //   after spmm1: S2 fp32 [0, 25.6MB), ZUV fp32 [25.6, 27.7MB)
  unsigned char* S1q = (unsigned char*)wsb;
  float* S2  = (float*)wsb;
  float* ZUV = (float*)(wsb + (size_t)N_NODES * NCLASS * sizeof(float));
  // Region B [51.2MB, 102.4MB): Hhi/Hlo; after GEMM2 dead -> ZU
  char* rB = wsb + (size_t)N_NODES * NHID * sizeof(float);
  unsigned short* Hhi = (unsigned short*)rB;
  unsigned short* Hlo = Hhi + (size_t)N_NODES * NHID;
  float* ZU = (float*)rB;                  // 2048*128
  // Split weights + row_ptr parked in d_out (dead until the final GEMM)
  unsigned short* W1Thi = (unsigned short*)out;
  unsigned short* W1Tlo = W1Thi + NHID * NFEAT;
  unsigned short* W2Thi = W1Tlo + NHID * NFEAT;
  unsigned short* W2Tlo = W2Thi + NCLASS * NHID;
  int* row_ptr = (int*)(W2Tlo + NCLASS * NHID);   // 50001 ints

  // 0) fused prep: row_ptr + weight transpose/split (one launch)
  prep_all<<<(N_EDGES + 255) / 256, 256, 0, stream>>>(
      adj_row, row_ptr, W1, W1Thi, W1Tlo, W2, W2Thi, W2Tlo);

  // 1) S1q = q24(x @ W1)  (wide MFMA BM=64, A split on the fly, B direct)
  gemm_mfma_wide<true, 2>
      <<<dim3(NHID / 128, (N_NODES + 63) / 64), 256, 0, stream>>>(
      x, nullptr, nullptr, W1Thi, W1Tlo,
      nullptr, S1q, N_NODES, NHID, NFEAT);

  // 2) Hhi/Hlo = split(relu(A @ S1 + b1))   (interleaved q24 gather)
  spmm256_q24_split<<<N_NODES / 4, 256, 0, stream>>>(
      S1q, row_ptr, adj_col, adj_val, (const float4*)b1, Hhi, Hlo);

  // 3) S2 = H @ W2  (wide MFMA BM=64, A pre-split, B direct, fp32 out)
  gemm_mfma_wide<false, 0>
      <<<dim3(NCLASS / 128, (N_NODES + 63) / 64), 256, 0, stream>>>(
      nullptr, Hhi, Hlo, W2Thi, W2Tlo,
      S2, nullptr, N_NODES, NCLASS, NHID);

  // 4) ZUV = (A @ S2 + b2)[concat(u,v)]  — only the 4096 rows the head uses
  spmm128_f32_list<<<(2 * N_UV) / 4, 256, 0, stream>>>(
      (const float4*)S2, row_ptr, adj_col, adj_val, (const float4*)b2,
      u, v, (float4*)ZUV);

  // 5) ZU = ZUV[0:2048] @ We^T  (BT = We as stored)
  gemm_mfma_split<0>
      <<<dim3(NCLASS / 128, N_UV / 128), 256, 0, stream>>>(
      ZUV, We, ZU, N_UV, NCLASS, NCLASS);

  // 6) out = sigmoid(ZU @ ZUV[2048:4096]^T)
  gemm_mfma_split<1>
      <<<dim3(N_UV / 128, N_UV / 128), 256, 0, stream>>>(
      ZU, ZUV + (size_t)N_UV * NCLASS, out, N_UV, N_UV, NCLASS);
}

// Round 7
// 365.543 us; speedup vs baseline: 1.6625x; 1.0129x over previous
//
#include <hip/hip_runtime.h>
#include <hip/hip_bf16.h>
#include <math.h>

// ---------------------------------------------------------------------------
// Problem constants (from reference)
// ---------------------------------------------------------------------------
#define N_NODES 50000
#define N_EDGES 800000
#define NFEAT   512
#define NHID    256
#define NCLASS  128
#define N_UV    2048

// q24 fixed-point: scale 2^19, range +-16 (|S1|<~5 -> wide margin)
#define Q24_SCALE  524288.0f
#define Q24_INV    1.9073486328125e-6f

typedef __bf16    bf16x8 __attribute__((ext_vector_type(8)));
typedef short     s16x8  __attribute__((ext_vector_type(8)));
typedef float     f32x4  __attribute__((ext_vector_type(4)));

struct __attribute__((packed)) U3 { unsigned a, b, c; };  // 12B dwordx3 view

__device__ __forceinline__ unsigned short bf16_rn(float f) {
  unsigned u = __float_as_uint(f);
  u += 0x7fffu + ((u >> 16) & 1u);
  return (unsigned short)(u >> 16);
}
__device__ __forceinline__ float bf16_to_f(unsigned short h) {
  return __uint_as_float(((unsigned)h) << 16);
}
// 4 x 24-bit signed little-endian values from 3 dwords
__device__ __forceinline__ void unpack24(unsigned a, unsigned b, unsigned c,
                                         int& e0, int& e1, int& e2, int& e3) {
  e0 = ((int)(a << 8)) >> 8;
  e1 = ((int)((b << 16) | ((a >> 24) << 8))) >> 8;
  e2 = ((int)((c << 24) | ((b >> 16) << 8))) >> 8;
  e3 = ((int)c) >> 8;
}

#define LDSPAD 72   // 64 + 8 shorts: keeps 16B alignment, breaks pow2 stride

// ---------------------------------------------------------------------------
// WIDE GEMM: C[M,N] = A[M,K] @ BT[N,K]^T, split-bf16 3-term.
// r16 config (best measured: 100.7us GEMM1): BM=64 / 256-thr / 4 waves
// (1Mx4N, per-wave 64x32, acc 4x2 = 32 AGPR), 4 blocks/CU, LDS 18.4KB,
// B direct-from-global (L2-resident weights), B hoisted before A prefetch.
// OMODE: 0 = fp32, 2 = interleaved q24 (3B/elem), 3 = fp32 + bias[col].
// r17: bias param for the new layer-2 reassociated tiny GEMM.
// ---------------------------------------------------------------------------
template <bool ASPLIT, int OMODE>
__global__ __launch_bounds__(256, 4) void gemm_mfma_wide(
    const float* __restrict__ Af,
    const unsigned short* __restrict__ Ahi, const unsigned short* __restrict__ Alo,
    const unsigned short* __restrict__ BThi, const unsigned short* __restrict__ BTlo,
    float* __restrict__ C, unsigned char* __restrict__ Cq,
    const float* __restrict__ bias, int M, int N, int K) {
  __shared__ unsigned short sAh[64 * LDSPAD];
  __shared__ unsigned short sAl[64 * LDSPAD];

  const int tid  = threadIdx.x;
  const int lane = tid & 63;
  const int wave = tid >> 6;           // 0..3
  const int wn   = wave << 5;          // 0,32,64,96
  const int lm   = lane & 15;
  const int quad = lane >> 4;
  const int m0   = blockIdx.y * 64;
  const int n0   = blockIdx.x * 128;

  // staging coordinates (BK=64, 256 threads, 64 rows)
  const int r32 = tid >> 4;            // 0..15 (fp32: 16 rows/pass, 4 passes)
  const int c32 = (tid & 15) * 4;      // float4 col
  const int r16 = tid >> 3;            // 0..31 (bf16: 32 rows/pass, 2 passes)
  const int c16 = (tid & 7) * 8;       // s16x8 col

  float4 pA[4]; s16x8 pAh[2], pAl[2];

  f32x4 acc[4][2];
#pragma unroll
  for (int i = 0; i < 4; ++i)
#pragma unroll
    for (int j = 0; j < 2; ++j)
#pragma unroll
      for (int r = 0; r < 4; ++r) acc[i][j][r] = 0.f;

#define LOAD_TILE(k0)                                                          \
  do {                                                                         \
    if (ASPLIT) {                                                              \
      _Pragma("unroll") for (int p = 0; p < 4; ++p) {                          \
        const int m = m0 + p * 16 + r32;                                       \
        pA[p] = make_float4(0.f, 0.f, 0.f, 0.f);                               \
        if (m < M) pA[p] = *(const float4*)&Af[(size_t)m * K + (k0) + c32];    \
      }                                                                        \
    } else {                                                                   \
      _Pragma("unroll") for (int p = 0; p < 2; ++p) {                          \
        const int m = m0 + p * 32 + r16;                                       \
        _Pragma("unroll") for (int e = 0; e < 8; ++e) { pAh[p][e] = 0; pAl[p][e] = 0; } \
        if (m < M) {                                                           \
          pAh[p] = *(const s16x8*)&Ahi[(size_t)m * K + (k0) + c16];            \
          pAl[p] = *(const s16x8*)&Alo[(size_t)m * K + (k0) + c16];            \
        }                                                                      \
      }                                                                        \
    }                                                                          \
  } while (0)

#define SPLIT4W(v, hv, lv)                                                     \
  hv.x = bf16_rn(v.x); lv.x = bf16_rn(v.x - bf16_to_f(hv.x));                  \
  hv.y = bf16_rn(v.y); lv.y = bf16_rn(v.y - bf16_to_f(hv.y));                  \
  hv.z = bf16_rn(v.z); lv.z = bf16_rn(v.z - bf16_to_f(hv.z));                  \
  hv.w = bf16_rn(v.w); lv.w = bf16_rn(v.w - bf16_to_f(hv.w));

#define STORE_TILE()                                                           \
  do {                                                                         \
    if (ASPLIT) {                                                              \
      _Pragma("unroll") for (int p = 0; p < 4; ++p) {                          \
        ushort4 hv, lv; SPLIT4W(pA[p], hv, lv);                                \
        const int row = p * 16 + r32;                                          \
        *(ushort4*)&sAh[row * LDSPAD + c32] = hv;                              \
        *(ushort4*)&sAl[row * LDSPAD + c32] = lv;                              \
      }                                                                        \
    } else {                                                                   \
      _Pragma("unroll") for (int p = 0; p < 2; ++p) {                          \
        const int row = p * 32 + r16;                                          \
        *(s16x8*)&sAh[row * LDSPAD + c16] = pAh[p];                            \
        *(s16x8*)&sAl[row * LDSPAD + c16] = pAl[p];                            \
      }                                                                        \
    }                                                                          \
  } while (0)

  LOAD_TILE(0);

  // B fragment row bases (direct-from-global, L2-resident weights)
  const unsigned short* Bhrow = BThi + (size_t)(n0 + wn + lm) * K;
  const unsigned short* Blrow = BTlo + (size_t)(n0 + wn + lm) * K;

  for (int k0 = 0; k0 < K; k0 += 64) {
    if (k0) __syncthreads();      // WAR: prior iter's frag reads complete
    STORE_TILE();
    __syncthreads();              // RAW: stores visible

    // B fragments for THIS K-tile, issued BEFORE the A prefetch (r14).
    bf16x8 bH[2][2], bL[2][2];
#pragma unroll
    for (int ks = 0; ks < 2; ++ks)
#pragma unroll
      for (int j = 0; j < 2; ++j) {
        const size_t off = (size_t)(j * 16) * K + k0 + ks * 32 + quad * 8;
        bH[ks][j] = __builtin_bit_cast(bf16x8, *(const s16x8*)(Bhrow + off));
        bL[ks][j] = __builtin_bit_cast(bf16x8, *(const s16x8*)(Blrow + off));
      }

    if (k0 + 64 < K) LOAD_TILE(k0 + 64);   // prefetch next tile (newest vmem)

#pragma unroll
    for (int ks = 0; ks < 2; ++ks) {
      const int koff = ks * 32 + quad * 8;
#pragma unroll
      for (int i = 0; i < 4; ++i) {
        const int r = i * 16 + lm;
        const bf16x8 aH = __builtin_bit_cast(bf16x8, *(const s16x8*)&sAh[r * LDSPAD + koff]);
        const bf16x8 aL = __builtin_bit_cast(bf16x8, *(const s16x8*)&sAl[r * LDSPAD + koff]);
#pragma unroll
        for (int j = 0; j < 2; ++j) {
          acc[i][j] = __builtin_amdgcn_mfma_f32_16x16x32_bf16(aH, bH[ks][j], acc[i][j], 0, 0, 0);
          acc[i][j] = __builtin_amdgcn_mfma_f32_16x16x32_bf16(aH, bL[ks][j], acc[i][j], 0, 0, 0);
          acc[i][j] = __builtin_amdgcn_mfma_f32_16x16x32_bf16(aL, bH[ks][j], acc[i][j], 0, 0, 0);
        }
      }
    }
  }

  // ---- epilogue: C/D layout col=lane&15, row=quad*4+reg ----
#pragma unroll
  for (int i = 0; i < 4; ++i)
#pragma unroll
    for (int j = 0; j < 2; ++j) {
      const int col = n0 + wn + j * 16 + lm;
      const float bb = (OMODE == 3) ? bias[col] : 0.f;
#pragma unroll
      for (int r = 0; r < 4; ++r) {
        const int row = m0 + i * 16 + quad * 4 + r;
        if (row < M) {
          float v = acc[i][j][r];
          if (OMODE == 2) {
            int q = __float2int_rn(v * Q24_SCALE);
            q = q > 8388607 ? 8388607 : (q < -8388608 ? -8388608 : q);
            unsigned char* p = Cq + ((size_t)row * N + col) * 3;
            p[0] = (unsigned char)(q & 0xFF);
            p[1] = (unsigned char)((q >> 8) & 0xFF);
            p[2] = (unsigned char)((q >> 16) & 0xFF);
          } else if (OMODE == 3) {
            C[(size_t)row * N + col] = v + bb;
          } else {
            C[(size_t)row * N + col] = v;
          }
        }
      }
    }
#undef LOAD_TILE
#undef STORE_TILE
#undef SPLIT4W
}

// ---------------------------------------------------------------------------
// Original 256-thread split-bf16 MFMA GEMM (r11, known-good) — used for the
// two small head GEMMs where A and B both come from fp32 on the fly.
// 128x128 tile, BK=64, 4 waves 2x2, launch_bounds(256,2).
// OMODE: 0 = fp32 C, 1 = sigmoid fp32 C.
// ---------------------------------------------------------------------------
template <int OMODE>
__global__ __launch_bounds__(256, 2) void gemm_mfma_split(
    const float* __restrict__ Af, const float* __restrict__ BTf,
    float* __restrict__ C, int M, int N, int K) {
  __shared__ unsigned short sAh[128 * LDSPAD];
  __shared__ unsigned short sAl[128 * LDSPAD];
  __shared__ unsigned short sBh[128 * LDSPAD];
  __shared__ unsigned short sBl[128 * LDSPAD];

  const int tid  = threadIdx.x;
  const int lane = tid & 63;
  const int wave = tid >> 6;
  const int wm   = (wave >> 1) << 6;
  const int wn   = (wave & 1) << 6;
  const int lm   = lane & 15;
  const int quad = lane >> 4;
  const int m0   = blockIdx.y * 128;
  const int n0   = blockIdx.x * 128;

  const int r32 = tid >> 4;            // 0..15
  const int c32 = (tid & 15) * 4;      // float4 col

  float4 pA[8];
  float4 pB[8];

  f32x4 acc[4][4];
#pragma unroll
  for (int i = 0; i < 4; ++i)
#pragma unroll
    for (int j = 0; j < 4; ++j)
#pragma unroll
      for (int r = 0; r < 4; ++r) acc[i][j][r] = 0.f;

#define LOAD_TILE(k0)                                                          \
  do {                                                                         \
    _Pragma("unroll") for (int p = 0; p < 8; ++p) {                            \
      const int m = m0 + p * 16 + r32;                                         \
      pA[p] = make_float4(0.f, 0.f, 0.f, 0.f);                                 \
      if (m < M) pA[p] = *(const float4*)&Af[(size_t)m * K + (k0) + c32];      \
    }                                                                          \
    _Pragma("unroll") for (int p = 0; p < 8; ++p) {                            \
      const int n = n0 + p * 16 + r32;                                         \
      pB[p] = *(const float4*)&BTf[(size_t)n * K + (k0) + c32];                \
    }                                                                          \
  } while (0)

#define SPLIT4(v, hv, lv)                                                      \
  hv.x = bf16_rn(v.x); lv.x = bf16_rn(v.x - bf16_to_f(hv.x));                  \
  hv.y = bf16_rn(v.y); lv.y = bf16_rn(v.y - bf16_to_f(hv.y));                  \
  hv.z = bf16_rn(v.z); lv.z = bf16_rn(v.z - bf16_to_f(hv.z));                  \
  hv.w = bf16_rn(v.w); lv.w = bf16_rn(v.w - bf16_to_f(hv.w));

#define STORE_TILE()                                                           \
  do {                                                                         \
    _Pragma("unroll") for (int p = 0; p < 8; ++p) {                            \
      ushort4 hv, lv; SPLIT4(pA[p], hv, lv);                                   \
      const int row = p * 16 + r32;                                            \
      *(ushort4*)&sAh[row * LDSPAD + c32] = hv;                                \
      *(ushort4*)&sAl[row * LDSPAD + c32] = lv;                                \
    }                                                                          \
    _Pragma("unroll") for (int p = 0; p < 8; ++p) {                            \
      ushort4 hv, lv; SPLIT4(pB[p], hv, lv);                                   \
      const int row = p * 16 + r32;                                            \
      *(ushort4*)&sBh[row * LDSPAD + c32] = hv;                                \
      *(ushort4*)&sBl[row * LDSPAD + c32] = lv;                                \
    }                                                                          \
  } while (0)

  LOAD_TILE(0);

  for (int k0 = 0; k0 < K; k0 += 64) {
    if (k0) __syncthreads();
    STORE_TILE();
    __syncthreads();
    if (k0 + 64 < K) LOAD_TILE(k0 + 64);

#pragma unroll
    for (int ks = 0; ks < 2; ++ks) {
      const int koff = ks * 32 + quad * 8;
      bf16x8 aH[4], aL[4], bH[4], bL[4];
#pragma unroll
      for (int i = 0; i < 4; ++i) {
        const int r = wm + i * 16 + lm;
        aH[i] = __builtin_bit_cast(bf16x8, *(const s16x8*)&sAh[r * LDSPAD + koff]);
        aL[i] = __builtin_bit_cast(bf16x8, *(const s16x8*)&sAl[r * LDSPAD + koff]);
      }
#pragma unroll
      for (int j = 0; j < 4; ++j) {
        const int r = wn + j * 16 + lm;
        bH[j] = __builtin_bit_cast(bf16x8, *(const s16x8*)&sBh[r * LDSPAD + koff]);
        bL[j] = __builtin_bit_cast(bf16x8, *(const s16x8*)&sBl[r * LDSPAD + koff]);
      }
#pragma unroll
      for (int i = 0; i < 4; ++i)
#pragma unroll
        for (int j = 0; j < 4; ++j) {
          acc[i][j] = __builtin_amdgcn_mfma_f32_16x16x32_bf16(aH[i], bH[j], acc[i][j], 0, 0, 0);
          acc[i][j] = __builtin_amdgcn_mfma_f32_16x16x32_bf16(aH[i], bL[j], acc[i][j], 0, 0, 0);
          acc[i][j] = __builtin_amdgcn_mfma_f32_16x16x32_bf16(aL[i], bH[j], acc[i][j], 0, 0, 0);
        }
    }
  }

#pragma unroll
  for (int i = 0; i < 4; ++i)
#pragma unroll
    for (int j = 0; j < 4; ++j) {
      const int col = n0 + wn + j * 16 + lm;
#pragma unroll
      for (int r = 0; r < 4; ++r) {
        const int row = m0 + wm + i * 16 + quad * 4 + r;
        if (row < M) {
          float v = acc[i][j][r];
          if (OMODE == 1) v = 1.f / (1.f + expf(-v));
          C[(size_t)row * N + col] = v;
        }
      }
    }
#undef LOAD_TILE
#undef STORE_TILE
#undef SPLIT4
}

// ---------------------------------------------------------------------------
// Fused prep: row_ptr build (edge-parallel) + W1/W2 transpose+split.
// ---------------------------------------------------------------------------
__global__ __launch_bounds__(256) void prep_all(
    const int* __restrict__ rows, int* __restrict__ row_ptr,
    const float* __restrict__ W1, unsigned short* __restrict__ W1Thi,
    unsigned short* __restrict__ W1Tlo,
    const float* __restrict__ W2, unsigned short* __restrict__ W2Thi,
    unsigned short* __restrict__ W2Tlo) {
  const int idx = blockIdx.x * 256 + threadIdx.x;
  if (idx < N_EDGES) {
    const int r = rows[idx];
    const int rprev = (idx == 0) ? -1 : rows[idx - 1];
    for (int n = rprev + 1; n <= r; ++n) row_ptr[n] = idx;
    if (idx == N_EDGES - 1)
      for (int n = r + 1; n <= N_NODES; ++n) row_ptr[n] = N_EDGES;
  }
  if (idx < NFEAT * NHID) {   // W1T[n*K+k] = split(W1[k*N+n]), K=NFEAT N=NHID
    const int n = idx / NFEAT;
    const int k = idx - n * NFEAT;
    const float f = W1[(size_t)k * NHID + n];
    const unsigned short h = bf16_rn(f);
    W1Thi[idx] = h;
    W1Tlo[idx] = bf16_rn(f - bf16_to_f(h));
  }
  if (idx < NHID * NCLASS) {  // W2T, K=NHID N=NCLASS
    const int n = idx / NHID;
    const int k = idx - n * NHID;
    const float f = W2[(size_t)k * NCLASS + n];
    const unsigned short h = bf16_rn(f);
    W2Thi[idx] = h;
    W2Tlo[idx] = bf16_rn(f - bf16_to_f(h));
  }
}

// ---------------------------------------------------------------------------
// SpMM F=256, interleaved q24 source (768B rows): one wave per node, lane =
// 12B dwordx3 = 4 elems (full row per wave). fp32 accumulate.
// 16-edge MASKED batches (r11). Fused bias+relu.
// r17: output H in fp32 (layer-2 reassociation consumes H via gather+tiny
// GEMM; the bf16 hi/lo split epilogue is gone).
// ---------------------------------------------------------------------------
__global__ __launch_bounds__(256, 4) void spmm256_q24_f32(
    const unsigned char* __restrict__ Sq, const int* __restrict__ row_ptr,
    const int* __restrict__ cols, const float* __restrict__ vals,
    const float4* __restrict__ bias4, float4* __restrict__ outF) {
  const int wave = threadIdx.x >> 6;
  const int lane = threadIdx.x & 63;
  const int node = blockIdx.x * 4 + wave;

  // lo/hi are wave-uniform (node is): pin to SGPRs for scalar loop control
  const int lou = __builtin_amdgcn_readfirstlane(row_ptr[node]);
  const int hiu = __builtin_amdgcn_readfirstlane(row_ptr[node + 1]);

  float4 acc = make_float4(0.f, 0.f, 0.f, 0.f);
  const int lane12 = lane * 12;

  for (int base = lou; base < hiu; base += 16) {
    int   c[16];
    float w[16];   // pre-scaled by Q24_INV; 0 for masked slots
    if (base + 16 <= hiu) {           // full batch: unclamped contiguous loads
#pragma unroll
      for (int t = 0; t < 16; ++t) {
        c[t] = cols[base + t];
        w[t] = vals[base + t] * Q24_INV;
      }
    } else {                          // final partial batch: clamp+mask
#pragma unroll
      for (int t = 0; t < 16; ++t) {
        const int idx = base + t;
        const int ide = idx < hiu ? idx : hiu - 1;   // valid duplicate row
        c[t] = cols[ide];
        w[t] = idx < hiu ? vals[ide] * Q24_INV : 0.f;
      }
    }
    U3 d[16];
#pragma unroll
    for (int t = 0; t < 16; ++t)
      d[t] = *(const U3*)&Sq[(size_t)c[t] * (NHID * 3) + lane12];
#pragma unroll
    for (int t = 0; t < 16; ++t) {
      int e0, e1, e2, e3;
      unpack24(d[t].a, d[t].b, d[t].c, e0, e1, e2, e3);
      acc.x = fmaf(w[t], (float)e0, acc.x);
      acc.y = fmaf(w[t], (float)e1, acc.y);
      acc.z = fmaf(w[t], (float)e2, acc.z);
      acc.w = fmaf(w[t], (float)e3, acc.w);
    }
  }

  const float4 b = bias4[lane];
  acc.x = fmaxf(acc.x + b.x, 0.f);
  acc.y = fmaxf(acc.y + b.y, 0.f);
  acc.z = fmaxf(acc.z + b.z, 0.f);
  acc.w = fmaxf(acc.w + b.w, 0.f);

  outF[(size_t)node * 64 + lane] = acc;   // 256 f32 = 64 float4/row
}

// ---------------------------------------------------------------------------
// SpMM F=256 over the 4096 LISTED nodes only (concat(u,v)) — the layer-2
// reassociation (A[uv,:]@H)@W2+b2 needs only these rows. One wave per list
// entry, lane = one float4 (full 1KB row per wave), 16-edge masked batches.
// fp32 gather from H (L3-resident 51.2MB), fp32 out ZUV2 [4096 x 256].
// ---------------------------------------------------------------------------
__global__ __launch_bounds__(256, 4) void spmm256_f32_list(
    const float4* __restrict__ H4, const int* __restrict__ row_ptr,
    const int* __restrict__ cols, const float* __restrict__ vals,
    const int* __restrict__ u, const int* __restrict__ v,
    float4* __restrict__ out4) {
  const int wave = threadIdx.x >> 6;
  const int lane = threadIdx.x & 63;
  const int idx  = blockIdx.x * 4 + wave;          // 0..4095
  const int node = idx < N_UV ? u[idx] : v[idx - N_UV];

  const int lou = __builtin_amdgcn_readfirstlane(row_ptr[node]);
  const int hiu = __builtin_amdgcn_readfirstlane(row_ptr[node + 1]);

  float4 acc = make_float4(0.f, 0.f, 0.f, 0.f);

  for (int base = lou; base < hiu; base += 16) {
    int   c[16];
    float w[16];
    if (base + 16 <= hiu) {
#pragma unroll
      for (int t = 0; t < 16; ++t) { c[t] = cols[base + t]; w[t] = vals[base + t]; }
    } else {
#pragma unroll
      for (int t = 0; t < 16; ++t) {
        const int e = base + t;
        const int ie = e < hiu ? e : hiu - 1;
        c[t] = cols[ie];
        w[t] = e < hiu ? vals[ie] : 0.f;
      }
    }
    float4 r[16];
#pragma unroll
    for (int t = 0; t < 16; ++t) r[t] = H4[(size_t)c[t] * 64 + lane];
#pragma unroll
    for (int t = 0; t < 16; ++t) {
      acc.x = fmaf(w[t], r[t].x, acc.x); acc.y = fmaf(w[t], r[t].y, acc.y);
      acc.z = fmaf(w[t], r[t].z, acc.z); acc.w = fmaf(w[t], r[t].w, acc.w);
    }
  }

  out4[(size_t)idx * 64 + lane] = acc;
}

// ---------------------------------------------------------------------------
// Launch
// ---------------------------------------------------------------------------
extern "C" void kernel_launch(void* const* d_in, const int* in_sizes, int n_in,
                              void* d_out, int out_size, void* d_ws, size_t ws_size,
                              hipStream_t stream) {
  const int*   u       = (const int*)  d_in[0];
  const int*   v       = (const int*)  d_in[1];
  const float* x       = (const float*)d_in[2];
  const int*   adj_row = (const int*)  d_in[3];
  const int*   adj_col = (const int*)  d_in[4];
  const float* adj_val = (const float*)d_in[5];
  const float* W1      = (const float*)d_in[6];
  const float* b1      = (const float*)d_in[7];
  const float* W2      = (const float*)d_in[8];
  const float* b2      = (const float*)d_in[9];
  const float* We      = (const float*)d_in[10];
  float* out = (float*)d_out;

  char* wsb = (char*)d_ws;
  // Region A [0, 51.2MB):
  //   S1q interleaved q24 38.4MB at [0, 38.4MB); dead after spmm1.
  //   then: ZUV2 fp32 [0, 4MB), ZUV fp32 [4MB, 6MB), ZU fp32 [6MB, 7MB)
  unsigned char* S1q = (unsigned char*)wsb;
  float* ZUV2 = (float*)wsb;                                   // 4096 x 256
  float* ZUV  = (float*)(wsb + (4u << 20));                    // 4096 x 128
  float* ZU   = (float*)(wsb + (6u << 20));                    // 2048 x 128
  // Region B [51.2MB, 102.4MB): H fp32 50000 x 256 = 51.2MB
  float* Hf = (float*)(wsb + (size_t)N_NODES * NHID * sizeof(float));
  // Split weights + row_ptr parked in d_out (dead before the final GEMM)
  unsigned short* W1Thi = (unsigned short*)out;
  unsigned short* W1Tlo = W1Thi + NHID * NFEAT;
  unsigned short* W2Thi = W1Tlo + NHID * NFEAT;
  unsigned short* W2Tlo = W2Thi + NCLASS * NHID;
  int* row_ptr = (int*)(W2Tlo + NCLASS * NHID);   // 50001 ints

  // 0) fused prep: row_ptr + weight transpose/split (one launch)
  prep_all<<<(N_EDGES + 255) / 256, 256, 0, stream>>>(
      adj_row, row_ptr, W1, W1Thi, W1Tlo, W2, W2Thi, W2Tlo);

  // 1) S1q = q24(x @ W1)  (wide MFMA BM=64, A split on the fly, B direct)
  gemm_mfma_wide<true, 2>
      <<<dim3(NHID / 128, (N_NODES + 63) / 64), 256, 0, stream>>>(
      x, nullptr, nullptr, W1Thi, W1Tlo,
      nullptr, S1q, nullptr, N_NODES, NHID, NFEAT);

  // 2) Hf = relu(A @ S1 + b1)   (interleaved q24 gather, fp32 out)
  spmm256_q24_f32<<<N_NODES / 4, 256, 0, stream>>>(
      S1q, row_ptr, adj_col, adj_val, (const float4*)b1, (float4*)Hf);

  // 3) ZUV2 = A[concat(u,v),:] @ Hf   (4096 listed rows only — GEMM3 over
  //    all 50000 rows is eliminated by reassociating (A@H)@W2)
  spmm256_f32_list<<<(2 * N_UV) / 4, 256, 0, stream>>>(
      (const float4*)Hf, row_ptr, adj_col, adj_val, u, v, (float4*)ZUV2);

  // 4) ZUV = ZUV2 @ W2 + b2   (tiny: 4096 x 256 x 128)
  gemm_mfma_wide<true, 3>
      <<<dim3(NCLASS / 128, (2 * N_UV) / 64), 256, 0, stream>>>(
      ZUV2, nullptr, nullptr, W2Thi, W2Tlo,
      ZUV, nullptr, b2, 2 * N_UV, NCLASS, NHID);

  // 5) ZU = ZUV[0:2048] @ We^T  (BT = We as stored)
  gemm_mfma_split<0>
      <<<dim3(NCLASS / 128, N_UV / 128), 256, 0, stream>>>(
      ZUV, We, ZU, N_UV, NCLASS, NCLASS);

  // 6) out = sigmoid(ZU @ ZUV[2048:4096]^T)
  gemm_mfma_split<1>
      <<<dim3(N_UV / 128, N_UV / 128), 256, 0, stream>>>(
      ZU, ZUV + (size_t)N_UV * NCLASS, out, N_UV, N_UV, NCLASS);
}

// Round 8
// 365.248 us; speedup vs baseline: 1.6639x; 1.0008x over previous
//
#include <hip/hip_runtime.h>
#include <hip/hip_bf16.h>
#include <math.h>

// ---------------------------------------------------------------------------
// Problem constants (from reference)
// ---------------------------------------------------------------------------
#define N_NODES 50000
#define N_EDGES 800000
#define NFEAT   512
#define NHID    256
#define NCLASS  128
#define N_UV    2048

// q24 fixed-point: scale 2^19, range +-16 (|S1|<~5 -> wide margin)
#define Q24_SCALE  524288.0f
#define Q24_INV    1.9073486328125e-6f

typedef __bf16    bf16x8 __attribute__((ext_vector_type(8)));
typedef short     s16x8  __attribute__((ext_vector_type(8)));
typedef float     f32x4  __attribute__((ext_vector_type(4)));

struct __attribute__((packed)) U3 { unsigned a, b, c; };  // 12B dwordx3 view

__device__ __forceinline__ unsigned short bf16_rn(float f) {
  unsigned u = __float_as_uint(f);
  u += 0x7fffu + ((u >> 16) & 1u);
  return (unsigned short)(u >> 16);
}
__device__ __forceinline__ float bf16_to_f(unsigned short h) {
  return __uint_as_float(((unsigned)h) << 16);
}
// 4 x 24-bit signed little-endian values from 3 dwords
__device__ __forceinline__ void unpack24(unsigned a, unsigned b, unsigned c,
                                         int& e0, int& e1, int& e2, int& e3) {
  e0 = ((int)(a << 8)) >> 8;
  e1 = ((int)((b << 16) | ((a >> 24) << 8))) >> 8;
  e2 = ((int)((c << 24) | ((b >> 16) << 8))) >> 8;
  e3 = ((int)c) >> 8;
}

#define LDSPAD 72   // 64 + 8 shorts: keeps 16B alignment, breaks pow2 stride

// ---------------------------------------------------------------------------
// WIDE GEMM: C[M,N] = A[M,K] @ BT[N,K]^T, split-bf16 3-term.
// BM=64 / 256-thr / 4 waves (1Mx4N, per-wave 64x32, acc 4x2 = 32 AGPR),
// B direct-from-global (L2-resident weights), B hoisted before A prefetch.
//
// r18: LDS DOUBLE-BUFFER -> ONE barrier per K-tile (was 2). r16/r17
// counters (Mfma 16, VALU 22, 60/97us pure stall) say the barrier drains
// dominate. Store tile t+1 into buf[(t+1)&1] AFTER computing tile t from
// buf[t&1]; the WAR hazard is now 2 tiles apart so a single barrier per
// iteration gives both visibility and WAR safety. The A prefetch issues
// before compute and drains at the post-compute STORE, where it has had
// the whole MFMA phase to land. LDS 36.8KB -> still 4 blocks/CU.
// OMODE: 0 = fp32, 2 = interleaved q24 (3B/elem), 3 = fp32 + bias[col].
// ---------------------------------------------------------------------------
template <bool ASPLIT, int OMODE>
__global__ __launch_bounds__(256, 4) void gemm_mfma_wide(
    const float* __restrict__ Af,
    const unsigned short* __restrict__ Ahi, const unsigned short* __restrict__ Alo,
    const unsigned short* __restrict__ BThi, const unsigned short* __restrict__ BTlo,
    float* __restrict__ C, unsigned char* __restrict__ Cq,
    const float* __restrict__ bias, int M, int N, int K) {
  __shared__ unsigned short sAh[2][64 * LDSPAD];
  __shared__ unsigned short sAl[2][64 * LDSPAD];

  const int tid  = threadIdx.x;
  const int lane = tid & 63;
  const int wave = tid >> 6;           // 0..3
  const int wn   = wave << 5;          // 0,32,64,96
  const int lm   = lane & 15;
  const int quad = lane >> 4;
  const int m0   = blockIdx.y * 64;
  const int n0   = blockIdx.x * 128;

  // staging coordinates (BK=64, 256 threads, 64 rows)
  const int r32 = tid >> 4;            // 0..15 (fp32: 16 rows/pass, 4 passes)
  const int c32 = (tid & 15) * 4;      // float4 col
  const int r16 = tid >> 3;            // 0..31 (bf16: 32 rows/pass, 2 passes)
  const int c16 = (tid & 7) * 8;       // s16x8 col

  float4 pA[4]; s16x8 pAh[2], pAl[2];

  f32x4 acc[4][2];
#pragma unroll
  for (int i = 0; i < 4; ++i)
#pragma unroll
    for (int j = 0; j < 2; ++j)
#pragma unroll
      for (int r = 0; r < 4; ++r) acc[i][j][r] = 0.f;

#define LOAD_TILE(k0)                                                          \
  do {                                                                         \
    if (ASPLIT) {                                                              \
      _Pragma("unroll") for (int p = 0; p < 4; ++p) {                          \
        const int m = m0 + p * 16 + r32;                                       \
        pA[p] = make_float4(0.f, 0.f, 0.f, 0.f);                               \
        if (m < M) pA[p] = *(const float4*)&Af[(size_t)m * K + (k0) + c32];    \
      }                                                                        \
    } else {                                                                   \
      _Pragma("unroll") for (int p = 0; p < 2; ++p) {                          \
        const int m = m0 + p * 32 + r16;                                       \
        _Pragma("unroll") for (int e = 0; e < 8; ++e) { pAh[p][e] = 0; pAl[p][e] = 0; } \
        if (m < M) {                                                           \
          pAh[p] = *(const s16x8*)&Ahi[(size_t)m * K + (k0) + c16];            \
          pAl[p] = *(const s16x8*)&Alo[(size_t)m * K + (k0) + c16];            \
        }                                                                      \
      }                                                                        \
    }                                                                          \
  } while (0)

#define SPLIT4W(v, hv, lv)                                                     \
  hv.x = bf16_rn(v.x); lv.x = bf16_rn(v.x - bf16_to_f(hv.x));                  \
  hv.y = bf16_rn(v.y); lv.y = bf16_rn(v.y - bf16_to_f(hv.y));                  \
  hv.z = bf16_rn(v.z); lv.z = bf16_rn(v.z - bf16_to_f(hv.z));                  \
  hv.w = bf16_rn(v.w); lv.w = bf16_rn(v.w - bf16_to_f(hv.w));

#define STORE_TILE(buf)                                                        \
  do {                                                                         \
    if (ASPLIT) {                                                              \
      _Pragma("unroll") for (int p = 0; p < 4; ++p) {                          \
        ushort4 hv, lv; SPLIT4W(pA[p], hv, lv);                                \
        const int row = p * 16 + r32;                                          \
        *(ushort4*)&sAh[buf][row * LDSPAD + c32] = hv;                         \
        *(ushort4*)&sAl[buf][row * LDSPAD + c32] = lv;                         \
      }                                                                        \
    } else {                                                                   \
      _Pragma("unroll") for (int p = 0; p < 2; ++p) {                          \
        const int row = p * 32 + r16;                                          \
        *(s16x8*)&sAh[buf][row * LDSPAD + c16] = pAh[p];                       \
        *(s16x8*)&sAl[buf][row * LDSPAD + c16] = pAl[p];                       \
      }                                                                        \
    }                                                                          \
  } while (0)

  LOAD_TILE(0);
  STORE_TILE(0);

  // B fragment row bases (direct-from-global, L2-resident weights)
  const unsigned short* Bhrow = BThi + (size_t)(n0 + wn + lm) * K;
  const unsigned short* Blrow = BTlo + (size_t)(n0 + wn + lm) * K;

  __syncthreads();               // tile0 visible

  const int NT = K >> 6;
  for (int t = 0; t < NT; ++t) {
    const int k0  = t << 6;
    const int cur = t & 1;
    const unsigned short* bufh = &sAh[cur][0];
    const unsigned short* bufl = &sAl[cur][0];

    // B fragments for THIS K-tile first: compute's wait for B then leaves
    // the (newer) A prefetch in flight (vmcnt is FIFO).
    bf16x8 bH[2][2], bL[2][2];
#pragma unroll
    for (int ks = 0; ks < 2; ++ks)
#pragma unroll
      for (int j = 0; j < 2; ++j) {
        const size_t off = (size_t)(j * 16) * K + k0 + ks * 32 + quad * 8;
        bH[ks][j] = __builtin_bit_cast(bf16x8, *(const s16x8*)(Bhrow + off));
        bL[ks][j] = __builtin_bit_cast(bf16x8, *(const s16x8*)(Blrow + off));
      }

    if (t + 1 < NT) LOAD_TILE(k0 + 64);   // prefetch next tile into regs

#pragma unroll
    for (int ks = 0; ks < 2; ++ks) {
      const int koff = ks * 32 + quad * 8;
#pragma unroll
      for (int i = 0; i < 4; ++i) {
        const int r = i * 16 + lm;
        const bf16x8 aH = __builtin_bit_cast(bf16x8, *(const s16x8*)&bufh[r * LDSPAD + koff]);
        const bf16x8 aL = __builtin_bit_cast(bf16x8, *(const s16x8*)&bufl[r * LDSPAD + koff]);
#pragma unroll
        for (int j = 0; j < 2; ++j) {
          acc[i][j] = __builtin_amdgcn_mfma_f32_16x16x32_bf16(aH, bH[ks][j], acc[i][j], 0, 0, 0);
          acc[i][j] = __builtin_amdgcn_mfma_f32_16x16x32_bf16(aH, bL[ks][j], acc[i][j], 0, 0, 0);
          acc[i][j] = __builtin_amdgcn_mfma_f32_16x16x32_bf16(aL, bH[ks][j], acc[i][j], 0, 0, 0);
        }
      }
    }

    // store NEXT tile into the other buffer (WAR-safe: readers of that
    // buffer finished at the barrier ending iteration t-1)
    if (t + 1 < NT) STORE_TILE(cur ^ 1);
    __syncthreads();             // next tile visible; this iter's reads done
  }

  // ---- epilogue: C/D layout col=lane&15, row=quad*4+reg ----
#pragma unroll
  for (int i = 0; i < 4; ++i)
#pragma unroll
    for (int j = 0; j < 2; ++j) {
      const int col = n0 + wn + j * 16 + lm;
      const float bb = (OMODE == 3) ? bias[col] : 0.f;
#pragma unroll
      for (int r = 0; r < 4; ++r) {
        const int row = m0 + i * 16 + quad * 4 + r;
        if (row < M) {
          float v = acc[i][j][r];
          if (OMODE == 2) {
            int q = __float2int_rn(v * Q24_SCALE);
            q = q > 8388607 ? 8388607 : (q < -8388608 ? -8388608 : q);
            unsigned char* p = Cq + ((size_t)row * N + col) * 3;
            p[0] = (unsigned char)(q & 0xFF);
            p[1] = (unsigned char)((q >> 8) & 0xFF);
            p[2] = (unsigned char)((q >> 16) & 0xFF);
          } else if (OMODE == 3) {
            C[(size_t)row * N + col] = v + bb;
          } else {
            C[(size_t)row * N + col] = v;
          }
        }
      }
    }
#undef LOAD_TILE
#undef STORE_TILE
#undef SPLIT4W
}

// ---------------------------------------------------------------------------
// Original 256-thread split-bf16 MFMA GEMM (r11, known-good) — used for the
// two small head GEMMs where A and B both come from fp32 on the fly.
// 128x128 tile, BK=64, 4 waves 2x2, launch_bounds(256,2).
// OMODE: 0 = fp32 C, 1 = sigmoid fp32 C.
// ---------------------------------------------------------------------------
template <int OMODE>
__global__ __launch_bounds__(256, 2) void gemm_mfma_split(
    const float* __restrict__ Af, const float* __restrict__ BTf,
    float* __restrict__ C, int M, int N, int K) {
  __shared__ unsigned short sAh[128 * LDSPAD];
  __shared__ unsigned short sAl[128 * LDSPAD];
  __shared__ unsigned short sBh[128 * LDSPAD];
  __shared__ unsigned short sBl[128 * LDSPAD];

  const int tid  = threadIdx.x;
  const int lane = tid & 63;
  const int wave = tid >> 6;
  const int wm   = (wave >> 1) << 6;
  const int wn   = (wave & 1) << 6;
  const int lm   = lane & 15;
  const int quad = lane >> 4;
  const int m0   = blockIdx.y * 128;
  const int n0   = blockIdx.x * 128;

  const int r32 = tid >> 4;            // 0..15
  const int c32 = (tid & 15) * 4;      // float4 col

  float4 pA[8];
  float4 pB[8];

  f32x4 acc[4][4];
#pragma unroll
  for (int i = 0; i < 4; ++i)
#pragma unroll
    for (int j = 0; j < 4; ++j)
#pragma unroll
      for (int r = 0; r < 4; ++r) acc[i][j][r] = 0.f;

#define LOAD_TILE(k0)                                                          \
  do {                                                                         \
    _Pragma("unroll") for (int p = 0; p < 8; ++p) {                            \
      const int m = m0 + p * 16 + r32;                                         \
      pA[p] = make_float4(0.f, 0.f, 0.f, 0.f);                                 \
      if (m < M) pA[p] = *(const float4*)&Af[(size_t)m * K + (k0) + c32];      \
    }                                                                          \
    _Pragma("unroll") for (int p = 0; p < 8; ++p) {                            \
      const int n = n0 + p * 16 + r32;                                         \
      pB[p] = *(const float4*)&BTf[(size_t)n * K + (k0) + c32];                \
    }                                                                          \
  } while (0)

#define SPLIT4(v, hv, lv)                                                      \
  hv.x = bf16_rn(v.x); lv.x = bf16_rn(v.x - bf16_to_f(hv.x));                  \
  hv.y = bf16_rn(v.y); lv.y = bf16_rn(v.y - bf16_to_f(hv.y));                  \
  hv.z = bf16_rn(v.z); lv.z = bf16_rn(v.z - bf16_to_f(hv.z));                  \
  hv.w = bf16_rn(v.w); lv.w = bf16_rn(v.w - bf16_to_f(hv.w));

#define STORE_TILE()                                                           \
  do {                                                                         \
    _Pragma("unroll") for (int p = 0; p < 8; ++p) {                            \
      ushort4 hv, lv; SPLIT4(pA[p], hv, lv);                                   \
      const int row = p * 16 + r32;                                            \
      *(ushort4*)&sAh[row * LDSPAD + c32] = hv;                                \
      *(ushort4*)&sAl[row * LDSPAD + c32] = lv;                                \
    }                                                                          \
    _Pragma("unroll") for (int p = 0; p < 8; ++p) {                            \
      ushort4 hv, lv; SPLIT4(pB[p], hv, lv);                                   \
      const int row = p * 16 + r32;                                            \
      *(ushort4*)&sBh[row * LDSPAD + c32] = hv;                                \
      *(ushort4*)&sBl[row * LDSPAD + c32] = lv;                                \
    }                                                                          \
  } while (0)

  LOAD_TILE(0);

  for (int k0 = 0; k0 < K; k0 += 64) {
    if (k0) __syncthreads();
    STORE_TILE();
    __syncthreads();
    if (k0 + 64 < K) LOAD_TILE(k0 + 64);

#pragma unroll
    for (int ks = 0; ks < 2; ++ks) {
      const int koff = ks * 32 + quad * 8;
      bf16x8 aH[4], aL[4], bH[4], bL[4];
#pragma unroll
      for (int i = 0; i < 4; ++i) {
        const int r = wm + i * 16 + lm;
        aH[i] = __builtin_bit_cast(bf16x8, *(const s16x8*)&sAh[r * LDSPAD + koff]);
        aL[i] = __builtin_bit_cast(bf16x8, *(const s16x8*)&sAl[r * LDSPAD + koff]);
      }
#pragma unroll
      for (int j = 0; j < 4; ++j) {
        const int r = wn + j * 16 + lm;
        bH[j] = __builtin_bit_cast(bf16x8, *(const s16x8*)&sBh[r * LDSPAD + koff]);
        bL[j] = __builtin_bit_cast(bf16x8, *(const s16x8*)&sBl[r * LDSPAD + koff]);
      }
#pragma unroll
      for (int i = 0; i < 4; ++i)
#pragma unroll
        for (int j = 0; j < 4; ++j) {
          acc[i][j] = __builtin_amdgcn_mfma_f32_16x16x32_bf16(aH[i], bH[j], acc[i][j], 0, 0, 0);
          acc[i][j] = __builtin_amdgcn_mfma_f32_16x16x32_bf16(aH[i], bL[j], acc[i][j], 0, 0, 0);
          acc[i][j] = __builtin_amdgcn_mfma_f32_16x16x32_bf16(aL[i], bH[j], acc[i][j], 0, 0, 0);
        }
    }
  }

#pragma unroll
  for (int i = 0; i < 4; ++i)
#pragma unroll
    for (int j = 0; j < 4; ++j) {
      const int col = n0 + wn + j * 16 + lm;
#pragma unroll
      for (int r = 0; r < 4; ++r) {
        const int row = m0 + wm + i * 16 + quad * 4 + r;
        if (row < M) {
          float v = acc[i][j][r];
          if (OMODE == 1) v = 1.f / (1.f + expf(-v));
          C[(size_t)row * N + col] = v;
        }
      }
    }
#undef LOAD_TILE
#undef STORE_TILE
#undef SPLIT4
}

// ---------------------------------------------------------------------------
// Fused prep: row_ptr build (edge-parallel) + W1/W2 transpose+split.
// ---------------------------------------------------------------------------
__global__ __launch_bounds__(256) void prep_all(
    const int* __restrict__ rows, int* __restrict__ row_ptr,
    const float* __restrict__ W1, unsigned short* __restrict__ W1Thi,
    unsigned short* __restrict__ W1Tlo,
    const float* __restrict__ W2, unsigned short* __restrict__ W2Thi,
    unsigned short* __restrict__ W2Tlo) {
  const int idx = blockIdx.x * 256 + threadIdx.x;
  if (idx < N_EDGES) {
    const int r = rows[idx];
    const int rprev = (idx == 0) ? -1 : rows[idx - 1];
    for (int n = rprev + 1; n <= r; ++n) row_ptr[n] = idx;
    if (idx == N_EDGES - 1)
      for (int n = r + 1; n <= N_NODES; ++n) row_ptr[n] = N_EDGES;
  }
  if (idx < NFEAT * NHID) {   // W1T[n*K+k] = split(W1[k*N+n]), K=NFEAT N=NHID
    const int n = idx / NFEAT;
    const int k = idx - n * NFEAT;
    const float f = W1[(size_t)k * NHID + n];
    const unsigned short h = bf16_rn(f);
    W1Thi[idx] = h;
    W1Tlo[idx] = bf16_rn(f - bf16_to_f(h));
  }
  if (idx < NHID * NCLASS) {  // W2T, K=NHID N=NCLASS
    const int n = idx / NHID;
    const int k = idx - n * NHID;
    const float f = W2[(size_t)k * NCLASS + n];
    const unsigned short h = bf16_rn(f);
    W2Thi[idx] = h;
    W2Tlo[idx] = bf16_rn(f - bf16_to_f(h));
  }
}

// ---------------------------------------------------------------------------
// SpMM F=256, interleaved q24 source (768B rows): one wave per node, lane =
// 12B dwordx3 = 4 elems (full row per wave). fp32 accumulate.
// 16-edge MASKED batches (r11). Fused bias+relu. fp32 H output (r17).
// ---------------------------------------------------------------------------
__global__ __launch_bounds__(256, 4) void spmm256_q24_f32(
    const unsigned char* __restrict__ Sq, const int* __restrict__ row_ptr,
    const int* __restrict__ cols, const float* __restrict__ vals,
    const float4* __restrict__ bias4, float4* __restrict__ outF) {
  const int wave = threadIdx.x >> 6;
  const int lane = threadIdx.x & 63;
  const int node = blockIdx.x * 4 + wave;

  // lo/hi are wave-uniform (node is): pin to SGPRs for scalar loop control
  const int lou = __builtin_amdgcn_readfirstlane(row_ptr[node]);
  const int hiu = __builtin_amdgcn_readfirstlane(row_ptr[node + 1]);

  float4 acc = make_float4(0.f, 0.f, 0.f, 0.f);
  const int lane12 = lane * 12;

  for (int base = lou; base < hiu; base += 16) {
    int   c[16];
    float w[16];   // pre-scaled by Q24_INV; 0 for masked slots
    if (base + 16 <= hiu) {           // full batch: unclamped contiguous loads
#pragma unroll
      for (int t = 0; t < 16; ++t) {
        c[t] = cols[base + t];
        w[t] = vals[base + t] * Q24_INV;
      }
    } else {                          // final partial batch: clamp+mask
#pragma unroll
      for (int t = 0; t < 16; ++t) {
        const int idx = base + t;
        const int ide = idx < hiu ? idx : hiu - 1;   // valid duplicate row
        c[t] = cols[ide];
        w[t] = idx < hiu ? vals[ide] * Q24_INV : 0.f;
      }
    }
    U3 d[16];
#pragma unroll
    for (int t = 0; t < 16; ++t)
      d[t] = *(const U3*)&Sq[(size_t)c[t] * (NHID * 3) + lane12];
#pragma unroll
    for (int t = 0; t < 16; ++t) {
      int e0, e1, e2, e3;
      unpack24(d[t].a, d[t].b, d[t].c, e0, e1, e2, e3);
      acc.x = fmaf(w[t], (float)e0, acc.x);
      acc.y = fmaf(w[t], (float)e1, acc.y);
      acc.z = fmaf(w[t], (float)e2, acc.z);
      acc.w = fmaf(w[t], (float)e3, acc.w);
    }
  }

  const float4 b = bias4[lane];
  acc.x = fmaxf(acc.x + b.x, 0.f);
  acc.y = fmaxf(acc.y + b.y, 0.f);
  acc.z = fmaxf(acc.z + b.z, 0.f);
  acc.w = fmaxf(acc.w + b.w, 0.f);

  outF[(size_t)node * 64 + lane] = acc;   // 256 f32 = 64 float4/row
}

// ---------------------------------------------------------------------------
// SpMM F=256 over the 4096 LISTED nodes only (concat(u,v)) — the layer-2
// reassociation (A[uv,:]@H)@W2+b2 needs only these rows. One wave per list
// entry, lane = one float4 (full 1KB row per wave), 16-edge masked batches.
// ---------------------------------------------------------------------------
__global__ __launch_bounds__(256, 4) void spmm256_f32_list(
    const float4* __restrict__ H4, const int* __restrict__ row_ptr,
    const int* __restrict__ cols, const float* __restrict__ vals,
    const int* __restrict__ u, const int* __restrict__ v,
    float4* __restrict__ out4) {
  const int wave = threadIdx.x >> 6;
  const int lane = threadIdx.x & 63;
  const int idx  = blockIdx.x * 4 + wave;          // 0..4095
  const int node = idx < N_UV ? u[idx] : v[idx - N_UV];

  const int lou = __builtin_amdgcn_readfirstlane(row_ptr[node]);
  const int hiu = __builtin_amdgcn_readfirstlane(row_ptr[node + 1]);

  float4 acc = make_float4(0.f, 0.f, 0.f, 0.f);

  for (int base = lou; base < hiu; base += 16) {
    int   c[16];
    float w[16];
    if (base + 16 <= hiu) {
#pragma unroll
      for (int t = 0; t < 16; ++t) { c[t] = cols[base + t]; w[t] = vals[base + t]; }
    } else {
#pragma unroll
      for (int t = 0; t < 16; ++t) {
        const int e = base + t;
        const int ie = e < hiu ? e : hiu - 1;
        c[t] = cols[ie];
        w[t] = e < hiu ? vals[ie] : 0.f;
      }
    }
    float4 r[16];
#pragma unroll
    for (int t = 0; t < 16; ++t) r[t] = H4[(size_t)c[t] * 64 + lane];
#pragma unroll
    for (int t = 0; t < 16; ++t) {
      acc.x = fmaf(w[t], r[t].x, acc.x); acc.y = fmaf(w[t], r[t].y, acc.y);
      acc.z = fmaf(w[t], r[t].z, acc.z); acc.w = fmaf(w[t], r[t].w, acc.w);
    }
  }

  out4[(size_t)idx * 64 + lane] = acc;
}

// ---------------------------------------------------------------------------
// Launch
// ---------------------------------------------------------------------------
extern "C" void kernel_launch(void* const* d_in, const int* in_sizes, int n_in,
                              void* d_out, int out_size, void* d_ws, size_t ws_size,
                              hipStream_t stream) {
  const int*   u       = (const int*)  d_in[0];
  const int*   v       = (const int*)  d_in[1];
  const float* x       = (const float*)d_in[2];
  const int*   adj_row = (const int*)  d_in[3];
  const int*   adj_col = (const int*)  d_in[4];
  const float* adj_val = (const float*)d_in[5];
  const float* W1      = (const float*)d_in[6];
  const float* b1      = (const float*)d_in[7];
  const float* W2      = (const float*)d_in[8];
  const float* b2      = (const float*)d_in[9];
  const float* We      = (const float*)d_in[10];
  float* out = (float*)d_out;

  char* wsb = (char*)d_ws;
  // Region A [0, 51.2MB):
  //   S1q interleaved q24 38.4MB at [0, 38.4MB); dead after spmm1.
  //   then: ZUV2 fp32 [0, 4MB), ZUV fp32 [4MB, 6MB), ZU fp32 [6MB, 7MB)
  unsigned char* S1q = (unsigned char*)wsb;
  float* ZUV2 = (float*)wsb;                                   // 4096 x 256
  float* ZUV  = (float*)(wsb + (4u << 20));                    // 4096 x 128
  float* ZU   = (float*)(wsb + (6u << 20));                    // 2048 x 128
  // Region B [51.2MB, 102.4MB): H fp32 50000 x 256 = 51.2MB
  float* Hf = (float*)(wsb + (size_t)N_NODES * NHID * sizeof(float));
  // Split weights + row_ptr parked in d_out (dead before the final GEMM)
  unsigned short* W1Thi = (unsigned short*)out;
  unsigned short* W1Tlo = W1Thi + NHID * NFEAT;
  unsigned short* W2Thi = W1Tlo + NHID * NFEAT;
  unsigned short* W2Tlo = W2Thi + NCLASS * NHID;
  int* row_ptr = (int*)(W2Tlo + NCLASS * NHID);   // 50001 ints

  // 0) fused prep: row_ptr + weight transpose/split (one launch)
  prep_all<<<(N_EDGES + 255) / 256, 256, 0, stream>>>(
      adj_row, row_ptr, W1, W1Thi, W1Tlo, W2, W2Thi, W2Tlo);

  // 1) S1q = q24(x @ W1)  (wide MFMA BM=64 dbuf, A split on the fly, B direct)
  gemm_mfma_wide<true, 2>
      <<<dim3(NHID / 128, (N_NODES + 63) / 64), 256, 0, stream>>>(
      x, nullptr, nullptr, W1Thi, W1Tlo,
      nullptr, S1q, nullptr, N_NODES, NHID, NFEAT);

  // 2) Hf = relu(A @ S1 + b1)   (interleaved q24 gather, fp32 out)
  spmm256_q24_f32<<<N_NODES / 4, 256, 0, stream>>>(
      S1q, row_ptr, adj_col, adj_val, (const float4*)b1, (float4*)Hf);

  // 3) ZUV2 = A[concat(u,v),:] @ Hf   (4096 listed rows only)
  spmm256_f32_list<<<(2 * N_UV) / 4, 256, 0, stream>>>(
      (const float4*)Hf, row_ptr, adj_col, adj_val, u, v, (float4*)ZUV2);

  // 4) ZUV = ZUV2 @ W2 + b2   (tiny: 4096 x 256 x 128)
  gemm_mfma_wide<true, 3>
      <<<dim3(NCLASS / 128, (2 * N_UV) / 64), 256, 0, stream>>>(
      ZUV2, nullptr, nullptr, W2Thi, W2Tlo,
      ZUV, nullptr, b2, 2 * N_UV, NCLASS, NHID);

  // 5) ZU = ZUV[0:2048] @ We^T  (BT = We as stored)
  gemm_mfma_split<0>
      <<<dim3(NCLASS / 128, N_UV / 128), 256, 0, stream>>>(
      ZUV, We, ZU, N_UV, NCLASS, NCLASS);

  // 6) out = sigmoid(ZU @ ZUV[2048:4096]^T)
  gemm_mfma_split<1>
      <<<dim3(N_UV / 128, N_UV / 128), 256, 0, stream>>>(
      ZU, ZUV + (size_t)N_UV * NCLASS, out, N_UV, N_UV, NCLASS);
}

// Round 9
// 364.640 us; speedup vs baseline: 1.6666x; 1.0017x over previous
//
#include <hip/hip_runtime.h>
#include <hip/hip_bf16.h>
#include <math.h>

// ---------------------------------------------------------------------------
// Problem constants (from reference)
// ---------------------------------------------------------------------------
#define N_NODES 50000
#define N_EDGES 800000
#define NFEAT   512
#define NHID    256
#define NCLASS  128
#define N_UV    2048

// q24 fixed-point: scale 2^19, range +-16 (|S1|<~5 -> wide margin)
#define Q24_SCALE  524288.0f
#define Q24_INV    1.9073486328125e-6f

typedef __bf16    bf16x8 __attribute__((ext_vector_type(8)));
typedef short     s16x8  __attribute__((ext_vector_type(8)));
typedef float     f32x4  __attribute__((ext_vector_type(4)));

struct __attribute__((packed)) U3 { unsigned a, b, c; };  // 12B dwordx3 view

__device__ __forceinline__ unsigned short bf16_rn(float f) {
  unsigned u = __float_as_uint(f);
  u += 0x7fffu + ((u >> 16) & 1u);
  return (unsigned short)(u >> 16);
}
__device__ __forceinline__ float bf16_to_f(unsigned short h) {
  return __uint_as_float(((unsigned)h) << 16);
}
// 4 x 24-bit signed little-endian values from 3 dwords
__device__ __forceinline__ void unpack24(unsigned a, unsigned b, unsigned c,
                                         int& e0, int& e1, int& e2, int& e3) {
  e0 = ((int)(a << 8)) >> 8;
  e1 = ((int)((b << 16) | ((a >> 24) << 8))) >> 8;
  e2 = ((int)((c << 24) | ((b >> 16) << 8))) >> 8;
  e3 = ((int)c) >> 8;
}

#define LDSPAD 72   // 64 + 8 shorts: keeps 16B alignment, breaks pow2 stride

// ---------------------------------------------------------------------------
// WIDE GEMM: C[M,N] = A[M,K] @ BT[N,K]^T, split-bf16 3-term
// (Ahi*Bhi + Ahi*Blo + Alo*Bhi — 3-term REQUIRED per r6/r8 calibration).
// BM=64 / 256-thr / 4 waves (1Mx4N, per-wave 64x32, acc 4x2 = 32 AGPR),
// 4 blocks/CU, B direct-from-global (L2-resident), LDS dbuf 1-barrier loop.
// r18 note: dbuf was neutral vs 2-barrier (96.6us both) — GEMM1 is at this
// structure's floor (407 TF-eff on a skinny N=256/K=512 shape); kept dbuf.
// OMODE: 0 fp32 | 1 sigmoid fp32 | 2 q24 3B/elem | 3 fp32+bias |
//        5 HEAD-DUAL: blockIdx.y < M/128 -> B=(BThi,BTlo), bias, fp32 C;
//                     else B=(BThi2,BTlo2), bias2, bf16 hi/lo split Chi/Clo.
// ---------------------------------------------------------------------------
template <bool ASPLIT, int OMODE>
__global__ __launch_bounds__(256, 4) void gemm_mfma_wide(
    const float* __restrict__ Af,
    const unsigned short* __restrict__ Ahi, const unsigned short* __restrict__ Alo,
    const unsigned short* __restrict__ BThi, const unsigned short* __restrict__ BTlo,
    const unsigned short* __restrict__ BThi2, const unsigned short* __restrict__ BTlo2,
    float* __restrict__ C, unsigned char* __restrict__ Cq,
    unsigned short* __restrict__ Chi, unsigned short* __restrict__ Clo,
    const float* __restrict__ bias, const float* __restrict__ bias2,
    int M, int N, int K) {
  __shared__ unsigned short sAh[2][64 * LDSPAD];
  __shared__ unsigned short sAl[2][64 * LDSPAD];

  const int tid  = threadIdx.x;
  const int lane = tid & 63;
  const int wave = tid >> 6;           // 0..3
  const int wn   = wave << 5;          // 0,32,64,96
  const int lm   = lane & 15;
  const int quad = lane >> 4;
  const int m0   = blockIdx.y * 64;
  const int n0   = blockIdx.x * 128;

  // head-dual half select (OMODE 5): y-blocks [0, M/128) = primary half
  const bool vh = (OMODE == 5) && ((int)blockIdx.y >= (M >> 7));
  const unsigned short* selBh = (OMODE == 5 && vh) ? BThi2 : BThi;
  const unsigned short* selBl = (OMODE == 5 && vh) ? BTlo2 : BTlo;
  const float*          selBi = (OMODE == 5 && vh) ? bias2 : bias;

  // staging coordinates (BK=64, 256 threads, 64 rows)
  const int r32 = tid >> 4;            // 0..15 (fp32: 16 rows/pass, 4 passes)
  const int c32 = (tid & 15) * 4;      // float4 col
  const int r16 = tid >> 3;            // 0..31 (bf16: 32 rows/pass, 2 passes)
  const int c16 = (tid & 7) * 8;       // s16x8 col

  float4 pA[4]; s16x8 pAh[2], pAl[2];

  f32x4 acc[4][2];
#pragma unroll
  for (int i = 0; i < 4; ++i)
#pragma unroll
    for (int j = 0; j < 2; ++j)
#pragma unroll
      for (int r = 0; r < 4; ++r) acc[i][j][r] = 0.f;

#define LOAD_TILE(k0)                                                          \
  do {                                                                         \
    if (ASPLIT) {                                                              \
      _Pragma("unroll") for (int p = 0; p < 4; ++p) {                          \
        const int m = m0 + p * 16 + r32;                                       \
        pA[p] = make_float4(0.f, 0.f, 0.f, 0.f);                               \
        if (m < M) pA[p] = *(const float4*)&Af[(size_t)m * K + (k0) + c32];    \
      }                                                                        \
    } else {                                                                   \
      _Pragma("unroll") for (int p = 0; p < 2; ++p) {                          \
        const int m = m0 + p * 32 + r16;                                       \
        _Pragma("unroll") for (int e = 0; e < 8; ++e) { pAh[p][e] = 0; pAl[p][e] = 0; } \
        if (m < M) {                                                           \
          pAh[p] = *(const s16x8*)&Ahi[(size_t)m * K + (k0) + c16];            \
          pAl[p] = *(const s16x8*)&Alo[(size_t)m * K + (k0) + c16];            \
        }                                                                      \
      }                                                                        \
    }                                                                          \
  } while (0)

#define SPLIT4W(v, hv, lv)                                                     \
  hv.x = bf16_rn(v.x); lv.x = bf16_rn(v.x - bf16_to_f(hv.x));                  \
  hv.y = bf16_rn(v.y); lv.y = bf16_rn(v.y - bf16_to_f(hv.y));                  \
  hv.z = bf16_rn(v.z); lv.z = bf16_rn(v.z - bf16_to_f(hv.z));                  \
  hv.w = bf16_rn(v.w); lv.w = bf16_rn(v.w - bf16_to_f(hv.w));

#define STORE_TILE(buf)                                                        \
  do {                                                                         \
    if (ASPLIT) {                                                              \
      _Pragma("unroll") for (int p = 0; p < 4; ++p) {                          \
        ushort4 hv, lv; SPLIT4W(pA[p], hv, lv);                                \
        const int row = p * 16 + r32;                                          \
        *(ushort4*)&sAh[buf][row * LDSPAD + c32] = hv;                         \
        *(ushort4*)&sAl[buf][row * LDSPAD + c32] = lv;                         \
      }                                                                        \
    } else {                                                                   \
      _Pragma("unroll") for (int p = 0; p < 2; ++p) {                          \
        const int row = p * 32 + r16;                                          \
        *(s16x8*)&sAh[buf][row * LDSPAD + c16] = pAh[p];                       \
        *(s16x8*)&sAl[buf][row * LDSPAD + c16] = pAl[p];                       \
      }                                                                        \
    }                                                                          \
  } while (0)

  LOAD_TILE(0);
  STORE_TILE(0);

  // B fragment row bases (direct-from-global, L2-resident weights)
  const unsigned short* Bhrow = selBh + (size_t)(n0 + wn + lm) * K;
  const unsigned short* Blrow = selBl + (size_t)(n0 + wn + lm) * K;

  __syncthreads();               // tile0 visible

  const int NT = K >> 6;
  for (int t = 0; t < NT; ++t) {
    const int k0  = t << 6;
    const int cur = t & 1;
    const unsigned short* bufh = &sAh[cur][0];
    const unsigned short* bufl = &sAl[cur][0];

    // B fragments for THIS K-tile first (vmcnt FIFO: A prefetch stays live)
    bf16x8 bH[2][2], bL[2][2];
#pragma unroll
    for (int ks = 0; ks < 2; ++ks)
#pragma unroll
      for (int j = 0; j < 2; ++j) {
        const size_t off = (size_t)(j * 16) * K + k0 + ks * 32 + quad * 8;
        bH[ks][j] = __builtin_bit_cast(bf16x8, *(const s16x8*)(Bhrow + off));
        bL[ks][j] = __builtin_bit_cast(bf16x8, *(const s16x8*)(Blrow + off));
      }

    if (t + 1 < NT) LOAD_TILE(k0 + 64);   // prefetch next tile into regs

#pragma unroll
    for (int ks = 0; ks < 2; ++ks) {
      const int koff = ks * 32 + quad * 8;
#pragma unroll
      for (int i = 0; i < 4; ++i) {
        const int r = i * 16 + lm;
        const bf16x8 aH = __builtin_bit_cast(bf16x8, *(const s16x8*)&bufh[r * LDSPAD + koff]);
        const bf16x8 aL = __builtin_bit_cast(bf16x8, *(const s16x8*)&bufl[r * LDSPAD + koff]);
#pragma unroll
        for (int j = 0; j < 2; ++j) {
          acc[i][j] = __builtin_amdgcn_mfma_f32_16x16x32_bf16(aH, bH[ks][j], acc[i][j], 0, 0, 0);
          acc[i][j] = __builtin_amdgcn_mfma_f32_16x16x32_bf16(aH, bL[ks][j], acc[i][j], 0, 0, 0);
          acc[i][j] = __builtin_amdgcn_mfma_f32_16x16x32_bf16(aL, bH[ks][j], acc[i][j], 0, 0, 0);
        }
      }
    }

    if (t + 1 < NT) STORE_TILE(cur ^ 1);
    __syncthreads();             // next tile visible; this iter's reads done
  }

  // ---- epilogue: C/D layout col=lane&15, row=quad*4+reg ----
#pragma unroll
  for (int i = 0; i < 4; ++i)
#pragma unroll
    for (int j = 0; j < 2; ++j) {
      const int col = n0 + wn + j * 16 + lm;
      const float bb = (OMODE == 3 || OMODE == 5) ? selBi[col] : 0.f;
#pragma unroll
      for (int r = 0; r < 4; ++r) {
        const int row = m0 + i * 16 + quad * 4 + r;
        if (row < M) {
          float v = acc[i][j][r];
          if (OMODE == 2) {
            int q = __float2int_rn(v * Q24_SCALE);
            q = q > 8388607 ? 8388607 : (q < -8388608 ? -8388608 : q);
            unsigned char* p = Cq + ((size_t)row * N + col) * 3;
            p[0] = (unsigned char)(q & 0xFF);
            p[1] = (unsigned char)((q >> 8) & 0xFF);
            p[2] = (unsigned char)((q >> 16) & 0xFF);
          } else if (OMODE == 1) {
            C[(size_t)row * N + col] = 1.f / (1.f + expf(-v));
          } else if (OMODE == 3) {
            C[(size_t)row * N + col] = v + bb;
          } else if (OMODE == 5) {
            v += bb;
            if (!vh) {
              C[(size_t)row * N + col] = v;          // ZU fp32 (rows 0..M/2)
            } else {
              const unsigned short h = bf16_rn(v);   // ZV bf16 hi/lo split
              const size_t o = (size_t)(row - (M >> 1)) * N + col;
              Chi[o] = h;
              Clo[o] = bf16_rn(v - bf16_to_f(h));
            }
          } else {
            C[(size_t)row * N + col] = v;
          }
        }
      }
    }
#undef LOAD_TILE
#undef STORE_TILE
#undef SPLIT4W
}

// ---------------------------------------------------------------------------
// Fused prep: row_ptr build (edge-parallel) + W1/W2 transpose+split.
// ---------------------------------------------------------------------------
__global__ __launch_bounds__(256) void prep_all(
    const int* __restrict__ rows, int* __restrict__ row_ptr,
    const float* __restrict__ W1, unsigned short* __restrict__ W1Thi,
    unsigned short* __restrict__ W1Tlo,
    const float* __restrict__ W2, unsigned short* __restrict__ W2Thi,
    unsigned short* __restrict__ W2Tlo) {
  const int idx = blockIdx.x * 256 + threadIdx.x;
  if (idx < N_EDGES) {
    const int r = rows[idx];
    const int rprev = (idx == 0) ? -1 : rows[idx - 1];
    for (int n = rprev + 1; n <= r; ++n) row_ptr[n] = idx;
    if (idx == N_EDGES - 1)
      for (int n = r + 1; n <= N_NODES; ++n) row_ptr[n] = N_EDGES;
  }
  if (idx < NFEAT * NHID) {   // W1T[n*K+k] = split(W1[k*N+n]), K=NFEAT N=NHID
    const int n = idx / NFEAT;
    const int k = idx - n * NFEAT;
    const float f = W1[(size_t)k * NHID + n];
    const unsigned short h = bf16_rn(f);
    W1Thi[idx] = h;
    W1Tlo[idx] = bf16_rn(f - bf16_to_f(h));
  }
  if (idx < NHID * NCLASS) {  // W2T, K=NHID N=NCLASS
    const int n = idx / NHID;
    const int k = idx - n * NHID;
    const float f = W2[(size_t)k * NCLASS + n];
    const unsigned short h = bf16_rn(f);
    W2Thi[idx] = h;
    W2Tlo[idx] = bf16_rn(f - bf16_to_f(h));
  }
}

// ---------------------------------------------------------------------------
// r19 head fusion prep: W2eT[n][k] = (W2 @ We^T)^T = dot(W2[k,:], We[n,:]),
// split to bf16 hi/lo in BT layout [NCLASS][NHID]; b2e[n] = dot(b2, We[n,:]).
// zu = (zuv2@W2+b2)@We^T == zuv2@W2e + b2e  — eliminates the 16-block GEMM5.
// 32768 elems, 1/thread, 128-dot each (fp32, float4).
// ---------------------------------------------------------------------------
__global__ __launch_bounds__(256) void prep_w2e(
    const float* __restrict__ W2, const float* __restrict__ We,
    const float* __restrict__ b2,
    unsigned short* __restrict__ W2eThi, unsigned short* __restrict__ W2eTlo,
    float* __restrict__ b2e) {
  const int idx = blockIdx.x * 256 + threadIdx.x;   // 0..32767
  const int n = idx >> 8;          // 0..127
  const int k = idx & 255;         // 0..255
  const float4* wr = (const float4*)(We + (size_t)n * NCLASS);   // We row n
  const float4* ar = (const float4*)(W2 + (size_t)k * NCLASS);   // W2 row k
  float s = 0.f;
#pragma unroll
  for (int c = 0; c < NCLASS / 4; ++c) {
    const float4 a = ar[c], w = wr[c];
    s = fmaf(a.x, w.x, s); s = fmaf(a.y, w.y, s);
    s = fmaf(a.z, w.z, s); s = fmaf(a.w, w.w, s);
  }
  const unsigned short h = bf16_rn(s);
  W2eThi[idx] = h;
  W2eTlo[idx] = bf16_rn(s - bf16_to_f(h));
  if (idx < NCLASS) {              // b2e[idx] = dot(b2, We[idx,:])
    const float4* br = (const float4*)b2;
    const float4* w2 = (const float4*)(We + (size_t)idx * NCLASS);
    float t = 0.f;
#pragma unroll
    for (int c = 0; c < NCLASS / 4; ++c) {
      const float4 a = br[c], w = w2[c];
      t = fmaf(a.x, w.x, t); t = fmaf(a.y, w.y, t);
      t = fmaf(a.z, w.z, t); t = fmaf(a.w, w.w, t);
    }
    b2e[idx] = t;
  }
}

// ---------------------------------------------------------------------------
// SpMM F=256, interleaved q24 source (768B rows): one wave per node, lane =
// 12B dwordx3 = 4 elems (full row per wave). fp32 accumulate.
// 16-edge MASKED batches (r11). Fused bias+relu. fp32 H output (r17).
// ---------------------------------------------------------------------------
__global__ __launch_bounds__(256, 4) void spmm256_q24_f32(
    const unsigned char* __restrict__ Sq, const int* __restrict__ row_ptr,
    const int* __restrict__ cols, const float* __restrict__ vals,
    const float4* __restrict__ bias4, float4* __restrict__ outF) {
  const int wave = threadIdx.x >> 6;
  const int lane = threadIdx.x & 63;
  const int node = blockIdx.x * 4 + wave;

  // lo/hi are wave-uniform (node is): pin to SGPRs for scalar loop control
  const int lou = __builtin_amdgcn_readfirstlane(row_ptr[node]);
  const int hiu = __builtin_amdgcn_readfirstlane(row_ptr[node + 1]);

  float4 acc = make_float4(0.f, 0.f, 0.f, 0.f);
  const int lane12 = lane * 12;

  for (int base = lou; base < hiu; base += 16) {
    int   c[16];
    float w[16];   // pre-scaled by Q24_INV; 0 for masked slots
    if (base + 16 <= hiu) {           // full batch: unclamped contiguous loads
#pragma unroll
      for (int t = 0; t < 16; ++t) {
        c[t] = cols[base + t];
        w[t] = vals[base + t] * Q24_INV;
      }
    } else {                          // final partial batch: clamp+mask
#pragma unroll
      for (int t = 0; t < 16; ++t) {
        const int idx = base + t;
        const int ide = idx < hiu ? idx : hiu - 1;   // valid duplicate row
        c[t] = cols[ide];
        w[t] = idx < hiu ? vals[ide] * Q24_INV : 0.f;
      }
    }
    U3 d[16];
#pragma unroll
    for (int t = 0; t < 16; ++t)
      d[t] = *(const U3*)&Sq[(size_t)c[t] * (NHID * 3) + lane12];
#pragma unroll
    for (int t = 0; t < 16; ++t) {
      int e0, e1, e2, e3;
      unpack24(d[t].a, d[t].b, d[t].c, e0, e1, e2, e3);
      acc.x = fmaf(w[t], (float)e0, acc.x);
      acc.y = fmaf(w[t], (float)e1, acc.y);
      acc.z = fmaf(w[t], (float)e2, acc.z);
      acc.w = fmaf(w[t], (float)e3, acc.w);
    }
  }

  const float4 b = bias4[lane];
  acc.x = fmaxf(acc.x + b.x, 0.f);
  acc.y = fmaxf(acc.y + b.y, 0.f);
  acc.z = fmaxf(acc.z + b.z, 0.f);
  acc.w = fmaxf(acc.w + b.w, 0.f);

  outF[(size_t)node * 64 + lane] = acc;   // 256 f32 = 64 float4/row
}

// ---------------------------------------------------------------------------
// SpMM F=256 over the 4096 LISTED nodes only (concat(u,v)) — the layer-2
// reassociation (A[uv,:]@H)@W2+b2 needs only these rows. One wave per list
// entry, lane = one float4 (full 1KB row per wave), 16-edge masked batches.
// ---------------------------------------------------------------------------
__global__ __launch_bounds__(256, 4) void spmm256_f32_list(
    const float4* __restrict__ H4, const int* __restrict__ row_ptr,
    const int* __restrict__ cols, const float* __restrict__ vals,
    const int* __restrict__ u, const int* __restrict__ v,
    float4* __restrict__ out4) {
  const int wave = threadIdx.x >> 6;
  const int lane = threadIdx.x & 63;
  const int idx  = blockIdx.x * 4 + wave;          // 0..4095
  const int node = idx < N_UV ? u[idx] : v[idx - N_UV];

  const int lou = __builtin_amdgcn_readfirstlane(row_ptr[node]);
  const int hiu = __builtin_amdgcn_readfirstlane(row_ptr[node + 1]);

  float4 acc = make_float4(0.f, 0.f, 0.f, 0.f);

  for (int base = lou; base < hiu; base += 16) {
    int   c[16];
    float w[16];
    if (base + 16 <= hiu) {
#pragma unroll
      for (int t = 0; t < 16; ++t) { c[t] = cols[base + t]; w[t] = vals[base + t]; }
    } else {
#pragma unroll
      for (int t = 0; t < 16; ++t) {
        const int e = base + t;
        const int ie = e < hiu ? e : hiu - 1;
        c[t] = cols[ie];
        w[t] = e < hiu ? vals[ie] : 0.f;
      }
    }
    float4 r[16];
#pragma unroll
    for (int t = 0; t < 16; ++t) r[t] = H4[(size_t)c[t] * 64 + lane];
#pragma unroll
    for (int t = 0; t < 16; ++t) {
      acc.x = fmaf(w[t], r[t].x, acc.x); acc.y = fmaf(w[t], r[t].y, acc.y);
      acc.z = fmaf(w[t], r[t].z, acc.z); acc.w = fmaf(w[t], r[t].w, acc.w);
    }
  }

  out4[(size_t)idx * 64 + lane] = acc;
}

// ---------------------------------------------------------------------------
// Launch
// ---------------------------------------------------------------------------
extern "C" void kernel_launch(void* const* d_in, const int* in_sizes, int n_in,
                              void* d_out, int out_size, void* d_ws, size_t ws_size,
                              hipStream_t stream) {
  const int*   u       = (const int*)  d_in[0];
  const int*   v       = (const int*)  d_in[1];
  const float* x       = (const float*)d_in[2];
  const int*   adj_row = (const int*)  d_in[3];
  const int*   adj_col = (const int*)  d_in[4];
  const float* adj_val = (const float*)d_in[5];
  const float* W1      = (const float*)d_in[6];
  const float* b1      = (const float*)d_in[7];
  const float* W2      = (const float*)d_in[8];
  const float* b2      = (const float*)d_in[9];
  const float* We      = (const float*)d_in[10];
  float* out = (float*)d_out;

  char* wsb = (char*)d_ws;
  // Region A [0, 51.2MB):
  //   S1q interleaved q24 38.4MB at [0, 38.4MB); dead after spmm1.
  //   then: ZUV2 fp32 [0,4MB), ZU fp32 [4,5MB), ZVhi [5,5.5MB), ZVlo [5.5,6MB)
  unsigned char* S1q = (unsigned char*)wsb;
  float* ZUV2 = (float*)wsb;                                    // 4096 x 256
  float* ZU   = (float*)(wsb + (4u << 20));                     // 2048 x 128
  unsigned short* ZVhi = (unsigned short*)(wsb + (5u << 20));   // 2048 x 128
  unsigned short* ZVlo = (unsigned short*)(wsb + (5u << 20) + (512u << 10));
  // Region B [51.2MB, 102.4MB): H fp32 50000 x 256 = 51.2MB
  float* Hf = (float*)(wsb + (size_t)N_NODES * NHID * sizeof(float));
  // Split weights + row_ptr + W2e parked in d_out (dead before final GEMM)
  unsigned short* W1Thi = (unsigned short*)out;
  unsigned short* W1Tlo = W1Thi + NHID * NFEAT;
  unsigned short* W2Thi = W1Tlo + NHID * NFEAT;
  unsigned short* W2Tlo = W2Thi + NCLASS * NHID;
  int* row_ptr = (int*)(W2Tlo + NCLASS * NHID);                 // 50001 ints
  unsigned short* W2eThi = (unsigned short*)(row_ptr + N_NODES + 4);
  unsigned short* W2eTlo = W2eThi + NCLASS * NHID;
  float* b2e = (float*)(W2eTlo + NCLASS * NHID);                // 128 floats

  // 0) prep: row_ptr + weight transpose/split; W2e = W2@We^T (head fusion)
  prep_all<<<(N_EDGES + 255) / 256, 256, 0, stream>>>(
      adj_row, row_ptr, W1, W1Thi, W1Tlo, W2, W2Thi, W2Tlo);
  prep_w2e<<<(NCLASS * NHID) / 256, 256, 0, stream>>>(
      W2, We, b2, W2eThi, W2eTlo, b2e);

  // 1) S1q = q24(x @ W1)  (wide MFMA BM=64 dbuf, A split on the fly, B direct)
  gemm_mfma_wide<true, 2>
      <<<dim3(NHID / 128, (N_NODES + 63) / 64), 256, 0, stream>>>(
      x, nullptr, nullptr, W1Thi, W1Tlo, nullptr, nullptr,
      nullptr, S1q, nullptr, nullptr, nullptr, nullptr, N_NODES, NHID, NFEAT);

  // 2) Hf = relu(A @ S1 + b1)   (interleaved q24 gather, fp32 out)
  spmm256_q24_f32<<<N_NODES / 4, 256, 0, stream>>>(
      S1q, row_ptr, adj_col, adj_val, (const float4*)b1, (float4*)Hf);

  // 3) ZUV2 = A[concat(u,v),:] @ Hf   (4096 listed rows only)
  spmm256_f32_list<<<(2 * N_UV) / 4, 256, 0, stream>>>(
      (const float4*)Hf, row_ptr, adj_col, adj_val, u, v, (float4*)ZUV2);

  // 4) HEAD-DUAL (GEMM5 eliminated via W2e):
  //    rows 0..2047:  ZU = ZUV2u @ W2e + b2e      (fp32)
  //    rows 2048..:   ZV = ZUV2v @ W2  + b2       (bf16 hi/lo split)
  gemm_mfma_wide<true, 5>
      <<<dim3(NCLASS / 128, (2 * N_UV) / 64), 256, 0, stream>>>(
      ZUV2, nullptr, nullptr, W2eThi, W2eTlo, W2Thi, W2Tlo,
      ZU, nullptr, ZVhi, ZVlo, b2e, b2, 2 * N_UV, NCLASS, NHID);

  // 5) out = sigmoid(ZU @ ZV^T)   (wide kernel, B = pre-split ZV direct)
  gemm_mfma_wide<true, 1>
      <<<dim3(N_UV / 128, N_UV / 64), 256, 0, stream>>>(
      ZU, nullptr, nullptr, ZVhi, ZVlo, nullptr, nullptr,
      out, nullptr, nullptr, nullptr, nullptr, nullptr, N_UV, N_UV, NCLASS);
}